// Round 2
// baseline (545.064 us; speedup 1.0000x reference)
//
#include <hip/hip_runtime.h>
#include <math.h>

#define N_NODES 25000
#define N_EDGES 400000
#define HID 128
#define EDGE_F 16
#define ADY 64
#define INNER 160
#define MSG_F 273
#define HEADS 8

// element offsets inside d_out (h2 | coords | res2)
#define OUT_CRD (N_NODES * HID)
#define OUT_RES (N_NODES * (HID + 3))

// ws byte offsets (16-aligned)
// den: bf16 [25000][8]  = 400000 B
// cacc: f32 [25000][3]  = 300000 B
// hagg: bf16 [25000][128] = 6400000 B
#define FLAG_OFF 0
#define DEN_OFF  256
#define CACC_OFF 400256
#define HAGG_OFF 700256
#define MEMSET_BYTES 7100256
#define HBF_OFF  7100256             // h as bf16: 6.4 MB
#define YBF_OFF  13500256            // y as bf16: 3.2 MB
#define BIAS_OFF 16700256            // 6 bias tensors, bf16 (2304 B)
#define BW_OFF   16702560            // blocked (fragment-linear) weights

typedef unsigned short u16;
typedef unsigned int u32;
typedef unsigned long long u64;
typedef __attribute__((ext_vector_type(8))) short short8;
typedef __attribute__((ext_vector_type(4))) float f32x4;

__device__ __forceinline__ float bf2f(u16 v) {
    union { u32 u; float f; } x; x.u = ((u32)v) << 16; return x.f;
}
__device__ __forceinline__ u16 f2bf(float f) {
    union { float ff; u32 u; } x; x.ff = f;
    u32 u = x.u;
    u32 rounding = 0x7FFFu + ((u >> 16) & 1u);
    u += rounding;
    return (u16)(u >> 16);
}
__device__ __forceinline__ float silu(float z) {
    z = fminf(fmaxf(z, -30000.f), 30000.f);
    return z / (1.0f + __expf(-z));
}

// packed 2xbf16 atomic add (fire-and-forget). p must be 4B-aligned.
// low 16 bits of `packed` add to p[0], high 16 bits to p[1].
__device__ __forceinline__ void pk_add_bf16(u16* p, u32 packed) {
    asm volatile("global_atomic_pk_add_bf16 %0, %1, off"
                 :: "v"(p), "v"(packed) : "memory");
}

template<bool F32> __device__ __forceinline__ float ldg1(const void* p, size_t i) {
    if (F32) return ((const float*)p)[i];
    return bf2f(((const u16*)p)[i]);
}
template<bool F32> __device__ __forceinline__ void stg1(void* p, size_t i, float v) {
    if (F32) ((float*)p)[i] = v;
    else     ((u16*)p)[i] = f2bf(v);
}
__device__ __forceinline__ float ldany(const void* p, size_t i, bool f32) {
    return f32 ? ((const float*)p)[i] : bf2f(((const u16*)p)[i]);
}
// wave-level LDS fence (node kernel)
__device__ __forceinline__ void wave_lds_fence() {
    __builtin_amdgcn_wave_barrier();
    __builtin_amdgcn_s_waitcnt(0xc07f);   // lgkmcnt(0) only
    __builtin_amdgcn_wave_barrier();
}

// ---------------------------------------------------------------------------
// Fused preprocessing: per-block dtype detect + cvt + fragment-linear blockw.
// ---------------------------------------------------------------------------
struct CvtArgs {
    const void* src[8];
    u64 dstoff[8];
    int n[8];
};
struct BwArgs {
    const void* We1; const void* We2; const void* Wv; const void* Wa;
    const void* Wc;  const void* Wo;  const void* Wn1; const void* Wn2;
    const void* Wf1; const void* Wf2;
    u64 b1, b2, b3, b4, b5, b6, b7, b8;
};

__global__ __launch_bounds__(256)
void preproc_kernel(const void* hsrc, int* flag, char* ws, CvtArgs args, BwArgs bwa)
{
    __shared__ float red[256];
    __shared__ int sflag;
    const int t = threadIdx.x;
    {
        const u16* p = (const u16*)hsrc;
        float mx = 0.f;
        for (int i = 0; i < 8; i++) {
            int idx = (t * 8 + i) * 97;
            float v = fabsf(bf2f(p[idx * 2]));
            mx = fmaxf(mx, v);
        }
        red[t] = mx;
        __syncthreads();
        for (int s = 128; s > 0; s >>= 1) {
            if (t < s) red[t] = fmaxf(red[t], red[t + s]);
            __syncthreads();
        }
        if (t == 0) {
            sflag = (red[0] > 1e10f || red[0] == 0.f) ? 1 : 0;
            if (blockIdx.x == 0) flag[0] = sflag;
        }
        __syncthreads();
    }
    const bool f32 = (sflag != 0);
    const int g = blockIdx.x * 256 + t;
    const int stride = gridDim.x * 256;

    // ---- cvt: biases + h + y ----
    for (int ten = 0; ten < 8; ten++) {
        const void* s = args.src[ten];
        u16* d = (u16*)(ws + args.dstoff[ten]);
        const int n = args.n[ten];
        if (f32) {
            const float* sf = (const float*)s;
            for (int i = g; i < n; i += stride) d[i] = f2bf(sf[i]);
        } else {
            const u16* su = (const u16*)s;
            for (int i = g; i < n; i += stride) d[i] = su[i];
        }
    }

    // ---- fragment-linear blocked weights ----
    u16* b1 = (u16*)(ws + bwa.b1);
    u16* b2 = (u16*)(ws + bwa.b2);
    u16* b3 = (u16*)(ws + bwa.b3);
    u16* b4 = (u16*)(ws + bwa.b4);
    u16* b5 = (u16*)(ws + bwa.b5);
    u16* b6 = (u16*)(ws + bwa.b6);
    u16* b7 = (u16*)(ws + bwa.b7);
    u16* b8 = (u16*)(ws + bwa.b8);
    // We1P: [5c][2ks][10nt] tiles, K=320 logical (k==273 -> dup row 256)
    for (int i = g; i < 5*2*10*512; i += stride) {
        int tt = i >> 9, r = i & 511, l = r >> 3, j = r & 7;
        int c = tt / 20, ks = (tt / 10) % 2, nt = tt % 10;
        int k = c*64 + ks*32 + (l >> 4)*8 + j;
        int n = nt*16 + (l & 15);
        float v = 0.f;
        if (k < MSG_F)      v = ldany(bwa.We1, (size_t)k*INNER + n, f32);
        else if (k == 273)  v = ldany(bwa.We1, (size_t)256*INNER + n, f32);
        b1[i] = f2bf(v);
    }
    // We2P: [5 k5][10 nt], K=160
    for (int i = g; i < 5*10*512; i += stride) {
        int tt = i >> 9, r = i & 511, l = r >> 3, j = r & 7;
        int k5 = tt / 10, nt = tt % 10;
        int k = k5*32 + (l >> 4)*8 + j;
        int n = nt*16 + (l & 15);
        b2[i] = f2bf(ldany(bwa.We2, (size_t)k*INNER + n, f32));
    }
    // W3P: [5 k5][9 nt], K=160; n<128 Wv | n<136 Wa | n==136 Wc | else 0
    for (int i = g; i < 5*9*512; i += stride) {
        int tt = i >> 9, r = i & 511, l = r >> 3, j = r & 7;
        int k5 = tt / 9, nt = tt % 9;
        int k = k5*32 + (l >> 4)*8 + j;
        int n = nt*16 + (l & 15);
        float v = 0.f;
        if (n < 128)       v = ldany(bwa.Wv, (size_t)k*HID + n, f32);
        else if (n < 136)  v = ldany(bwa.Wa, (size_t)k*HEADS + (n-128), f32);
        else if (n == 136) v = ldany(bwa.Wc, (size_t)k, f32);
        b3[i] = f2bf(v);
    }
    // WoP: [4 cks][8 nt], K=128
    for (int i = g; i < 4*8*512; i += stride) {
        int tt = i >> 9, r = i & 511, l = r >> 3, j = r & 7;
        int cks = tt / 8, nt = tt % 8;
        int k = cks*32 + (l >> 4)*8 + j;
        int n = nt*16 + (l & 15);
        b4[i] = f2bf(ldany(bwa.Wo, (size_t)k*HID + n, f32));
    }
    // Wn1P: [4 cks][10 nt], K=128
    for (int i = g; i < 4*10*512; i += stride) {
        int tt = i >> 9, r = i & 511, l = r >> 3, j = r & 7;
        int cks = tt / 10, nt = tt % 10;
        int k = cks*32 + (l >> 4)*8 + j;
        int n = nt*16 + (l & 15);
        b5[i] = f2bf(ldany(bwa.Wn1, (size_t)k*INNER + n, f32));
    }
    // Wn2P: [5 k5][8 nt], K=160
    for (int i = g; i < 5*8*512; i += stride) {
        int tt = i >> 9, r = i & 511, l = r >> 3, j = r & 7;
        int k5 = tt / 8, nt = tt % 8;
        int k = k5*32 + (l >> 4)*8 + j;
        int n = nt*16 + (l & 15);
        b6[i] = f2bf(ldany(bwa.Wn2, (size_t)k*HID + n, f32));
    }
    // Wf1P / Wf2P: [2 ks][16 nt], K=64
    for (int i = g; i < 2*16*512; i += stride) {
        int tt = i >> 9, r = i & 511, l = r >> 3, j = r & 7;
        int ks = tt / 16, nt = tt % 16;
        int k = ks*32 + (l >> 4)*8 + j;
        int n = nt*16 + (l & 15);
        b7[i] = f2bf(ldany(bwa.Wf1, (size_t)k*256 + n, f32));
        b8[i] = f2bf(ldany(bwa.Wf2, (size_t)k*256 + n, f32));
    }
}

// ---------------------------------------------------------------------------
// MFMA edge kernel. Epilogue uses packed 2xbf16 atomics: adjacent N-columns
// live in lane pairs (col, col^1) with identical dst, so one shfl_xor + one
// global_atomic_pk_add_bf16 covers 2 values -> halves atomic op count AND
// halves atomic write bytes. cacc (coords) stays f32 for accuracy.
// ---------------------------------------------------------------------------
template<bool F32>   // applies to coords / a only
__device__ __forceinline__ void edge_body(
    const u16* __restrict__ hbf, const void* coords, const void* a,
    const int* __restrict__ src, const int* __restrict__ dst,
    const u16* __restrict__ We1P, const u16* __restrict__ We2P,
    const u16* __restrict__ W3P,
    const u16* __restrict__ cbe1, const u16* __restrict__ cbe2,
    u16* __restrict__ den, u16* __restrict__ hagg, float* __restrict__ cacc,
    u16* sPool, float* sdiff, float* srad, int* ssrc, int* sdstl)
{
    const int t   = threadIdx.x;
    const int w   = t >> 6;
    const int l   = t & 63;
    const int col = l & 15;
    const int q   = l >> 4;
    const int e0  = blockIdx.x * 64;
    const int l8  = l << 3;

    u16* sF  = sPool;               // [64][360]
    u16* sM1 = sPool;               // [64][168] (aliases sF)
    u16* sM2 = sPool + 64*168;      // [64][168]

    if (t < 64) {
        int e = e0 + t;
        int s = src[e], d = dst[e];
        ssrc[t] = s; sdstl[t] = d;
        float dx = ldg1<F32>(coords, (size_t)s*3+0) - ldg1<F32>(coords, (size_t)d*3+0);
        float dy = ldg1<F32>(coords, (size_t)s*3+1) - ldg1<F32>(coords, (size_t)d*3+1);
        float dz = ldg1<F32>(coords, (size_t)s*3+2) - ldg1<F32>(coords, (size_t)d*3+2);
        sdiff[t*4+0] = dx; sdiff[t*4+1] = dy; sdiff[t*4+2] = dz;
        float r2 = dx*dx + dy*dy + dz*dz;
        srad[t] = r2;
        sdiff[t*4+3] = 1.0f / (sqrtf(r2 + 1e-5f) + 1.0f);
    }
    __syncthreads();                                    // B1

    // ---- stage ALL f chunks (4 lanes per edge, pure bf16 copies) ----
    {
        int e = t >> 2, part = t & 3;
        int node_s = ssrc[e], node_d = sdstl[e];
        #pragma unroll
        for (int c = 0; c < 4; c++) {
            int node = (c < 2) ? node_s : node_d;
            int c0 = (c & 1) * 64 + part * 16;
            const uint4* gp = (const uint4*)(hbf + (size_t)node*HID + c0);
            *(uint4*)(&sF[e*360 + c*72 + part*16])     = gp[0];
            *(uint4*)(&sF[e*360 + c*72 + part*16 + 8]) = gp[1];
        }
        if (part < 2) {
            __align__(16) u16 tmp[16];
            #pragma unroll
            for (int j = 0; j < 16; j++) tmp[j] = 0;
            if (part == 0) {
                float r2 = srad[e];
                tmp[0] = f2bf(r2);                           // kc0 = radial hi
                for (int j = 0; j < 15; j++)
                    tmp[1+j] = f2bf(ldg1<F32>(a, (size_t)(e0+e)*EDGE_F + j));
            } else {
                tmp[0] = f2bf(ldg1<F32>(a, (size_t)(e0+e)*EDGE_F + 15));
                float r2 = srad[e];
                tmp[1] = f2bf(r2 - bf2f(f2bf(r2)));          // kc17 = radial lo
            }
            *(uint4*)(&sF[e*360 + 4*72 + part*16])     = ((uint4*)tmp)[0];
            *(uint4*)(&sF[e*360 + 4*72 + part*16 + 8]) = ((uint4*)tmp)[1];
        }
    }
    __syncthreads();                                    // B2

    // ---- GEMM1: K=288 effective ----
    f32x4 acc1[10];
    #pragma unroll
    for (int nt = 0; nt < 10; nt++) {
        float v = bf2f(cbe1[nt*16 + col]);
        acc1[nt] = (f32x4){v, v, v, v};
    }
    const u16* fbase = &sF[(w*16 + col)*360];
    #pragma unroll
    for (int c = 0; c < 4; c++) {
        #pragma unroll
        for (int ks = 0; ks < 2; ks++) {
            short8 af = *(const short8*)(fbase + c*72 + ks*32 + q*8);
            const u16* B1 = We1P + (((c*2 + ks)*10) << 9) + l8;
            #pragma unroll
            for (int nt = 0; nt < 10; nt++) {
                short8 b = *(const short8*)(B1 + (nt << 9));
                acc1[nt] = __builtin_amdgcn_mfma_f32_16x16x32_bf16(af, b, acc1[nt], 0, 0, 0);
            }
        }
    }
    {   // c=4, ks=0 only
        short8 af = *(const short8*)(fbase + 4*72 + q*8);
        const u16* B1 = We1P + ((8*10) << 9) + l8;
        #pragma unroll
        for (int nt = 0; nt < 10; nt++) {
            short8 b = *(const short8*)(B1 + (nt << 9));
            acc1[nt] = __builtin_amdgcn_mfma_f32_16x16x32_bf16(af, b, acc1[nt], 0, 0, 0);
        }
    }
    __syncthreads();                                    // B3 (sF dead)
    #pragma unroll
    for (int nt = 0; nt < 10; nt++)
        #pragma unroll
        for (int r = 0; r < 4; r++)
            sM1[(w*16 + q*4 + r)*168 + nt*16 + col] = f2bf(silu(acc1[nt][r]));
    __syncthreads();                                    // B4

    // ---- GEMM2: K=160 ----
    f32x4 acc2[10];
    #pragma unroll
    for (int nt = 0; nt < 10; nt++) {
        float v = bf2f(cbe2[nt*16 + col]);
        acc2[nt] = (f32x4){v, v, v, v};
    }
    const u16* m1base = &sM1[(w*16 + col)*168];
    #pragma unroll
    for (int k5 = 0; k5 < 5; k5++) {
        short8 af = *(const short8*)(m1base + k5*32 + q*8);
        const u16* B2 = We2P + ((k5*10) << 9) + l8;
        #pragma unroll
        for (int nt = 0; nt < 10; nt++) {
            short8 b = *(const short8*)(B2 + (nt << 9));
            acc2[nt] = __builtin_amdgcn_mfma_f32_16x16x32_bf16(af, b, acc2[nt], 0, 0, 0);
        }
    }
    #pragma unroll
    for (int nt = 0; nt < 10; nt++)
        #pragma unroll
        for (int r = 0; r < 4; r++)
            sM2[(w*16 + q*4 + r)*168 + nt*16 + col] = f2bf(silu(acc2[nt][r]));
    __syncthreads();                                    // B5

    // ---- GEMM3: N=144, K=160 ----
    f32x4 acc3[9];
    #pragma unroll
    for (int nt = 0; nt < 9; nt++) acc3[nt] = (f32x4){0.f, 0.f, 0.f, 0.f};
    const u16* m2base = &sM2[(w*16 + col)*168];
    #pragma unroll
    for (int k5 = 0; k5 < 5; k5++) {
        short8 af = *(const short8*)(m2base + k5*32 + q*8);
        const u16* B3 = W3P + ((k5*9) << 9) + l8;
        #pragma unroll
        for (int nt = 0; nt < 9; nt++) {
            short8 b = *(const short8*)(B3 + (nt << 9));
            acc3[nt] = __builtin_amdgcn_mfma_f32_16x16x32_bf16(af, b, acc3[nt], 0, 0, 0);
        }
    }

    // ---- epilogue: wave-local, no barrier ----
    int dstep[4];
    #pragma unroll
    for (int r = 0; r < 4; r++) dstep[r] = sdstl[w*16 + q*4 + r];

    float exv[4] = {0.f, 0.f, 0.f, 0.f};
    if (col < 8) {           // logits: head=col
        #pragma unroll
        for (int r = 0; r < 4; r++)
            exv[r] = __expf(fminf(fmaxf(acc3[8][r], -30.f), 30.f));
    }
    // den: packed bf16 pairs of heads (even col issues heads {col, col+1})
    {
        float exn[4];
        #pragma unroll
        for (int r = 0; r < 4; r++) exn[r] = __shfl_xor(exv[r], 1);
        if (col < 8 && (col & 1) == 0) {
            #pragma unroll
            for (int r = 0; r < 4; r++) {
                u32 pk = (u32)f2bf(exv[r]) | ((u32)f2bf(exn[r]) << 16);
                pk_add_bf16(&den[(size_t)dstep[r]*8 + col], pk);
            }
        }
    }
    if (col == 8) {          // coord scalar (f32 atomics, accuracy-critical)
        #pragma unroll
        for (int r = 0; r < 4; r++) {
            int idx = w*16 + q*4 + r;
            int dd = dstep[r];
            float invf = sdiff[idx*4 + 3];
            float lc = fminf(fmaxf(acc3[8][r], -1e6f), 1e6f) * invf;
            #pragma unroll
            for (int j = 0; j < 3; j++)
                atomicAdd(&cacc[(size_t)dd*3 + j], lc * sdiff[idx*4 + j]);
        }
    }
    // hagg: packed bf16 pairs across adjacent cols. Lane pair (col, col^1)
    // shares dstep (dst depends only on q,r). Even cols issue nt<4, odd nt>=4.
    const bool lo = (col & 1) == 0;
    const int cb = col & ~1;
    #pragma unroll
    for (int nt = 0; nt < 8; nt++) {
        float ex0 = __shfl(exv[0], q*16 + nt);
        float ex1 = __shfl(exv[1], q*16 + nt);
        float ex2 = __shfl(exv[2], q*16 + nt);
        float ex3 = __shfl(exv[3], q*16 + nt);
        float v0 = acc3[nt][0] * ex0;
        float v1 = acc3[nt][1] * ex1;
        float v2 = acc3[nt][2] * ex2;
        float v3 = acc3[nt][3] * ex3;
        float n0 = __shfl_xor(v0, 1);
        float n1 = __shfl_xor(v1, 1);
        float n2 = __shfl_xor(v2, 1);
        float n3 = __shfl_xor(v3, 1);
        if (lo ? (nt < 4) : (nt >= 4)) {
            int base = nt*16 + cb;
            u32 p0 = lo ? ((u32)f2bf(v0) | ((u32)f2bf(n0) << 16))
                        : ((u32)f2bf(n0) | ((u32)f2bf(v0) << 16));
            u32 p1 = lo ? ((u32)f2bf(v1) | ((u32)f2bf(n1) << 16))
                        : ((u32)f2bf(n1) | ((u32)f2bf(v1) << 16));
            u32 p2 = lo ? ((u32)f2bf(v2) | ((u32)f2bf(n2) << 16))
                        : ((u32)f2bf(n2) | ((u32)f2bf(v2) << 16));
            u32 p3 = lo ? ((u32)f2bf(v3) | ((u32)f2bf(n3) << 16))
                        : ((u32)f2bf(n3) | ((u32)f2bf(v3) << 16));
            pk_add_bf16(&hagg[(size_t)dstep[0]*HID + base], p0);
            pk_add_bf16(&hagg[(size_t)dstep[1]*HID + base], p1);
            pk_add_bf16(&hagg[(size_t)dstep[2]*HID + base], p2);
            pk_add_bf16(&hagg[(size_t)dstep[3]*HID + base], p3);
        }
    }
}

__global__ __launch_bounds__(256, 3)
void edge_kernel(const int* __restrict__ flag,
                 const u16* __restrict__ hbf, const void* coords, const void* a,
                 const int* __restrict__ src, const int* __restrict__ dst,
                 const u16* __restrict__ We1P, const u16* __restrict__ We2P,
                 const u16* __restrict__ W3P,
                 const u16* __restrict__ cbe1, const u16* __restrict__ cbe2,
                 u16* __restrict__ den, u16* __restrict__ hagg,
                 float* __restrict__ cacc)
{
    __shared__ __align__(16) u16 sPool[64*360];   // 46080 B
    __shared__ float sdiff[64*4];
    __shared__ float srad[64];
    __shared__ int   ssrc[64];
    __shared__ int   sdstl[64];
    if (*flag)
        edge_body<true>(hbf, coords, a, src, dst, We1P, We2P, W3P, cbe1, cbe2,
                        den, hagg, cacc, sPool, sdiff, srad, ssrc, sdstl);
    else
        edge_body<false>(hbf, coords, a, src, dst, We1P, We2P, W3P, cbe1, cbe2,
                         den, hagg, cacc, sPool, sdiff, srad, ssrc, sdstl);
}

// ---------------------------------------------------------------------------
// Barrier-free fused MFMA node kernel, fragment-linear B reads.
// ---------------------------------------------------------------------------
template<bool F32>   // applies to res / coords / out
__device__ __forceinline__ void node_body(
    const u16* __restrict__ hbf, const void* res, const void* coords,
    const u16* __restrict__ ybf,
    const u16* __restrict__ den, const u16* __restrict__ hagg,
    const float* __restrict__ cacc,
    const u16* __restrict__ WoP, const u16* __restrict__ Wn1P,
    const u16* __restrict__ Wn2P, const u16* __restrict__ Wf1P,
    const u16* __restrict__ Wf2P,
    const u16* __restrict__ cbn1, const u16* __restrict__ cbn2,
    const u16* __restrict__ cbf1, const u16* __restrict__ cbf2,
    void* out, u16* sScr)
{
    const int t = threadIdx.x;
    const int w = t >> 6, l = t & 63, col = l & 15, q = l >> 4;
    const int nodew = blockIdx.x * 64 + w * 16;
    const int mynode = nodew + col;
    const bool okA = mynode < N_NODES;
    const int l8 = l << 3;
    u16* sc = sScr + w * 16 * 168;

    int gm[4]; bool okC[4];
    #pragma unroll
    for (int r = 0; r < 4; r++) { gm[r] = nodew + q*4 + r; okC[r] = gm[r] < N_NODES; }

    f32x4 aF2[8];
    #pragma unroll
    for (int nt = 0; nt < 8; nt++) aF2[nt] = (f32x4){0.f,0.f,0.f,0.f};
    #pragma unroll
    for (int c = 0; c < 2; c++) {
        #pragma unroll
        for (int ks = 0; ks < 2; ks++) {
            const int kbase = c*64 + ks*32 + q*8;
            union { u16 s[8]; short8 v; } u;
            if (okA) {
                float dd = bf2f(den[(size_t)mynode*8 + (kbase >> 4)]);
                float inv = dd > 0.f ? 1.f/dd : 0.f;
                const short8 hv = *(const short8*)(hagg + (size_t)mynode*HID + kbase);
                #pragma unroll
                for (int j = 0; j < 8; j++)
                    u.s[j] = f2bf(bf2f((u16)hv[j]) * inv);
            } else {
                #pragma unroll
                for (int j = 0; j < 8; j++) u.s[j] = 0;
            }
            const u16* B = WoP + (((c*2 + ks)*8) << 9) + l8;
            #pragma unroll
            for (int nt = 0; nt < 8; nt++) {
                short8 b = *(const short8*)(B + (nt << 9));
                aF2[nt] = __builtin_amdgcn_mfma_f32_16x16x32_bf16(u.v, b, aF2[nt], 0, 0, 0);
            }
        }
    }

    f32x4 aFl[16];
    #pragma unroll
    for (int nt = 0; nt < 16; nt++) {
        float v = bf2f(cbf1[nt*16 + col]);
        aFl[nt] = (f32x4){v,v,v,v};
    }
    #pragma unroll
    for (int ks = 0; ks < 2; ks++) {
        short8 af;
        if (okA) af = *(const short8*)(ybf + (size_t)mynode*ADY + ks*32 + q*8);
        else { union { u16 s[8]; short8 v; } z; for (int j=0;j<8;j++) z.s[j]=0; af = z.v; }
        const u16* B = Wf1P + ((ks*16) << 9) + l8;
        #pragma unroll
        for (int nt = 0; nt < 16; nt++) {
            short8 b = *(const short8*)(B + (nt << 9));
            aFl[nt] = __builtin_amdgcn_mfma_f32_16x16x32_bf16(af, b, aFl[nt], 0, 0, 0);
        }
    }

    float h1c[8][4], r1c[8][4];
    {
        float xv[8][4], s[4], ss[4];
        #pragma unroll
        for (int r = 0; r < 4; r++) { s[r] = 0.f; ss[r] = 0.f; }
        #pragma unroll
        for (int nt = 0; nt < 8; nt++)
            #pragma unroll
            for (int r = 0; r < 4; r++) {
                float hv = okC[r] ? bf2f(hbf[(size_t)gm[r]*HID + nt*16 + col]) : 0.f;
                float x = hv + aF2[nt][r];
                xv[nt][r] = x; s[r] += x; ss[r] += x*x;
            }
        #pragma unroll
        for (int r = 0; r < 4; r++)
            for (int off = 1; off <= 8; off <<= 1) {
                s[r]  += __shfl_xor(s[r], off);
                ss[r] += __shfl_xor(ss[r], off);
            }
        #pragma unroll
        for (int r = 0; r < 4; r++) {
            float mu = s[r] * (1.f/128.f);
            float var = ss[r] * (1.f/128.f) - mu*mu;
            float rs = rsqrtf(fmaxf(var, 0.f) + 1e-5f);
            #pragma unroll
            for (int nt = 0; nt < 8; nt++) {
                float h1 = (xv[nt][r]-mu)*rs*(1.f+aFl[nt][r]) + aFl[nt+8][r];
                h1c[nt][r] = h1;
                float rv = okC[r] ? ldg1<F32>(res, (size_t)gm[r]*HID + nt*16 + col) : 0.f;
                r1c[nt][r] = rv + aF2[nt][r];
                sc[(q*4 + r)*168 + nt*16 + col] = f2bf(h1);
            }
        }
    }
    wave_lds_fence();

    f32x4 aT[10];
    #pragma unroll
    for (int nt = 0; nt < 10; nt++) {
        float v = bf2f(cbn1[nt*16 + col]);
        aT[nt] = (f32x4){v,v,v,v};
    }
    #pragma unroll
    for (int c = 0; c < 2; c++) {
        #pragma unroll
        for (int ks = 0; ks < 2; ks++) {
            short8 af = *(const short8*)(sc + col*168 + c*64 + ks*32 + q*8);
            const u16* B = Wn1P + (((c*2 + ks)*10) << 9) + l8;
            #pragma unroll
            for (int nt = 0; nt < 10; nt++) {
                short8 b = *(const short8*)(B + (nt << 9));
                aT[nt] = __builtin_amdgcn_mfma_f32_16x16x32_bf16(af, b, aT[nt], 0, 0, 0);
            }
        }
    }
    wave_lds_fence();
    #pragma unroll
    for (int nt = 0; nt < 10; nt++)
        #pragma unroll
        for (int r = 0; r < 4; r++)
            sc[(q*4 + r)*168 + nt*16 + col] = f2bf(silu(aT[nt][r]));
    wave_lds_fence();

    f32x4 aF3[8];
    #pragma unroll
    for (int nt = 0; nt < 8; nt++) {
        float v = bf2f(cbn2[nt*16 + col]);
        aF3[nt] = (f32x4){v,v,v,v};
    }
    #pragma unroll
    for (int k5 = 0; k5 < 5; k5++) {
        short8 af = *(const short8*)(sc + col*168 + k5*32 + q*8);
        const u16* B = Wn2P + ((k5*8) << 9) + l8;
        #pragma unroll
        for (int nt = 0; nt < 8; nt++) {
            short8 b = *(const short8*)(B + (nt << 9));
            aF3[nt] = __builtin_amdgcn_mfma_f32_16x16x32_bf16(af, b, aF3[nt], 0, 0, 0);
        }
    }

    #pragma unroll
    for (int nt = 0; nt < 16; nt++) {
        float v = bf2f(cbf2[nt*16 + col]);
        aFl[nt] = (f32x4){v,v,v,v};
    }
    #pragma unroll
    for (int ks = 0; ks < 2; ks++) {
        short8 af;
        if (okA) af = *(const short8*)(ybf + (size_t)mynode*ADY + ks*32 + q*8);
        else { union { u16 s[8]; short8 v; } z; for (int j=0;j<8;j++) z.s[j]=0; af = z.v; }
        const u16* B = Wf2P + ((ks*16) << 9) + l8;
        #pragma unroll
        for (int nt = 0; nt < 16; nt++) {
            short8 b = *(const short8*)(B + (nt << 9));
            aFl[nt] = __builtin_amdgcn_mfma_f32_16x16x32_bf16(af, b, aFl[nt], 0, 0, 0);
        }
    }

    {
        float xv[8][4], s[4], ss[4];
        #pragma unroll
        for (int r = 0; r < 4; r++) { s[r] = 0.f; ss[r] = 0.f; }
        #pragma unroll
        for (int nt = 0; nt < 8; nt++)
            #pragma unroll
            for (int r = 0; r < 4; r++) {
                float x = h1c[nt][r] + aF3[nt][r];
                xv[nt][r] = x; s[r] += x; ss[r] += x*x;
            }
        #pragma unroll
        for (int r = 0; r < 4; r++)
            for (int off = 1; off <= 8; off <<= 1) {
                s[r]  += __shfl_xor(s[r], off);
                ss[r] += __shfl_xor(ss[r], off);
            }
        #pragma unroll
        for (int r = 0; r < 4; r++) {
            float mu = s[r] * (1.f/128.f);
            float var = ss[r] * (1.f/128.f) - mu*mu;
            float rs = rsqrtf(fmaxf(var, 0.f) + 1e-5f);
            if (okC[r]) {
                #pragma unroll
                for (int nt = 0; nt < 8; nt++) {
                    int n = nt*16 + col;
                    float h2 = (xv[nt][r]-mu)*rs*(1.f+aFl[nt][r]) + aFl[nt+8][r];
                    stg1<F32>(out, (size_t)gm[r]*HID + n, h2);
                    stg1<F32>(out, (size_t)OUT_RES + (size_t)gm[r]*HID + n,
                              r1c[nt][r] + aF3[nt][r]);
                }
            }
        }
    }

    if (q == 0 && okA) {
        #pragma unroll
        for (int j = 0; j < 3; j++)
            stg1<F32>(out, (size_t)OUT_CRD + (size_t)mynode*3 + j,
                      ldg1<F32>(coords, (size_t)mynode*3 + j) + cacc[(size_t)mynode*3 + j]);
    }
}

__global__ __launch_bounds__(256, 2)
void node_kernel(const int* __restrict__ flag,
                 const u16* __restrict__ hbf, const void* res, const void* coords,
                 const u16* __restrict__ ybf,
                 const u16* __restrict__ den, const u16* __restrict__ hagg,
                 const float* __restrict__ cacc,
                 const u16* __restrict__ WoP, const u16* __restrict__ Wn1P,
                 const u16* __restrict__ Wn2P, const u16* __restrict__ Wf1P,
                 const u16* __restrict__ Wf2P,
                 const u16* __restrict__ cbn1, const u16* __restrict__ cbn2,
                 const u16* __restrict__ cbf1, const u16* __restrict__ cbf2,
                 void* out)
{
    __shared__ __align__(16) u16 sScr[4 * 16 * 168];
    if (*flag)
        node_body<true>(hbf, res, coords, ybf, den, hagg, cacc, WoP, Wn1P, Wn2P,
                        Wf1P, Wf2P, cbn1, cbn2, cbf1, cbf2, out, sScr);
    else
        node_body<false>(hbf, res, coords, ybf, den, hagg, cacc, WoP, Wn1P, Wn2P,
                         Wf1P, Wf2P, cbn1, cbn2, cbf1, cbf2, out, sScr);
}

// ---------------------------------------------------------------------------
extern "C" void kernel_launch(void* const* d_in, const int* in_sizes, int n_in,
                              void* d_out, int out_size, void* d_ws, size_t ws_size,
                              hipStream_t stream)
{
    const void* h      = d_in[0];
    const void* coords = d_in[1];
    const void* a      = d_in[2];
    const void* y      = d_in[3];
    const void* res    = d_in[4];
    const int* src     = (const int*)d_in[5];
    const int* dst     = (const int*)d_in[6];

    char* ws = (char*)d_ws;
    int*   flag = (int*)(ws + FLAG_OFF);
    u16*   den  = (u16*)(ws + DEN_OFF);
    float* cacc = (float*)(ws + CACC_OFF);
    u16*   hagg = (u16*)(ws + HAGG_OFF);
    u16*   hbf  = (u16*)(ws + HBF_OFF);
    u16*   ybf  = (u16*)(ws + YBF_OFF);

    // convert list: 6 biases + h + y
    CvtArgs args;
    const int cvtn[8]   = {160, 160, 160, 128, 256, 256, N_NODES*HID, N_NODES*ADY};
    const int cvtsrc[8] = {8, 10, 16, 18, 20, 22, 0, 3};
    u64 boff[8];
    u64 bo = BIAS_OFF;
    for (int i = 0; i < 6; i++) {
        boff[i] = bo;
        bo += ((u64)cvtn[i] * 2 + 15) & ~(u64)15;
    }
    boff[6] = HBF_OFF;
    boff[7] = YBF_OFF;
    for (int i = 0; i < 8; i++) {
        args.src[i] = d_in[cvtsrc[i]];
        args.dstoff[i] = boff[i];
        args.n[i] = cvtn[i];
    }
    const u16* cbe1 = (const u16*)(ws + boff[0]);
    const u16* cbe2 = (const u16*)(ws + boff[1]);
    const u16* cbn1 = (const u16*)(ws + boff[2]);
    const u16* cbn2 = (const u16*)(ws + boff[3]);
    const u16* cbf1 = (const u16*)(ws + boff[4]);
    const u16* cbf2 = (const u16*)(ws + boff[5]);

    // fragment-linear blocked weights
    BwArgs bwa;
    bwa.We1 = d_in[7];  bwa.We2 = d_in[9];  bwa.Wv = d_in[12]; bwa.Wa = d_in[13];
    bwa.Wc  = d_in[11]; bwa.Wo  = d_in[14]; bwa.Wn1 = d_in[15]; bwa.Wn2 = d_in[17];
    bwa.Wf1 = d_in[19]; bwa.Wf2 = d_in[21];
    bwa.b1 = BW_OFF;
    bwa.b2 = bwa.b1 + (u64)5*2*10*512*2;   // 102400 B
    bwa.b3 = bwa.b2 + (u64)5*10*512*2;     //  51200 B
    bwa.b4 = bwa.b3 + (u64)5*9*512*2;      //  46080 B
    bwa.b5 = bwa.b4 + (u64)4*8*512*2;      //  32768 B
    bwa.b6 = bwa.b5 + (u64)4*10*512*2;     //  40960 B
    bwa.b7 = bwa.b6 + (u64)5*8*512*2;      //  40960 B
    bwa.b8 = bwa.b7 + (u64)2*16*512*2;     //  32768 B
    const u16* We1P = (const u16*)(ws + bwa.b1);
    const u16* We2P = (const u16*)(ws + bwa.b2);
    const u16* W3P  = (const u16*)(ws + bwa.b3);
    const u16* WoP  = (const u16*)(ws + bwa.b4);
    const u16* Wn1P = (const u16*)(ws + bwa.b5);
    const u16* Wn2P = (const u16*)(ws + bwa.b6);
    const u16* Wf1P = (const u16*)(ws + bwa.b7);
    const u16* Wf2P = (const u16*)(ws + bwa.b8);

    hipMemsetAsync(d_ws, 0, MEMSET_BYTES, stream);

    preproc_kernel<<<256, 256, 0, stream>>>(h, flag, ws, args, bwa);

    edge_kernel<<<N_EDGES/64, 256, 0, stream>>>(flag, hbf, coords, a, src, dst,
                                                We1P, We2P, W3P, cbe1, cbe2,
                                                den, hagg, cacc);

    node_kernel<<<(N_NODES + 63)/64, 256, 0, stream>>>(
        flag, hbf, res, coords, ybf, den, hagg, cacc,
        WoP, Wn1P, Wn2P, Wf1P, Wf2P, cbn1, cbn2, cbf1, cbf2, d_out);
}

// Round 3
// 527.966 us; speedup vs baseline: 1.0324x; 1.0324x over previous
//
#include <hip/hip_runtime.h>
#include <math.h>

#define N_NODES 25000
#define N_EDGES 400000
#define HID 128
#define EDGE_F 16
#define ADY 64
#define INNER 160
#define MSG_F 273
#define HEADS 8

// element offsets inside d_out (h2 | coords | res2)
#define OUT_CRD (N_NODES * HID)
#define OUT_RES (N_NODES * (HID + 3))

// ws byte offsets (16-aligned)
#define FLAG_OFF 0
#define DEN_OFF  256                    // f32 [25000][8]   = 800000
#define CACC_OFF 800256                 // f32 [25000][3]   = 300000
#define HAGG_OFF 1100256                // f32 [25000][128] = 12800000
#define CNT_OFF  13900256               // int [25000] histogram
#define CUR_OFF  14000256               // int [25000] scan/cursor
#define PERM_OFF 14100256               // int [400000] dst-sorted edge ids
#define MEMSET_BYTES 14000256           // zero flag..cnt (cursor/perm fully overwritten)
#define HBF_OFF  15700256               // h as bf16: 6.4 MB
#define YBF_OFF  22100256               // y as bf16: 3.2 MB
#define BIAS_OFF 25300256               // 6 bias tensors, bf16
#define BW_OFF   25302560               // blocked (fragment-linear) weights

#define SCR_STRIDE 145                  // f32 scratch row stride (bank-spread)

typedef unsigned short u16;
typedef unsigned int u32;
typedef unsigned long long u64;
typedef __attribute__((ext_vector_type(8))) short short8;
typedef __attribute__((ext_vector_type(4))) float f32x4;

__device__ __forceinline__ float bf2f(u16 v) {
    union { u32 u; float f; } x; x.u = ((u32)v) << 16; return x.f;
}
__device__ __forceinline__ u16 f2bf(float f) {
    union { float ff; u32 u; } x; x.ff = f;
    u32 u = x.u;
    u32 rounding = 0x7FFFu + ((u >> 16) & 1u);
    u += rounding;
    return (u16)(u >> 16);
}
__device__ __forceinline__ float silu(float z) {
    z = fminf(fmaxf(z, -30000.f), 30000.f);
    return z / (1.0f + __expf(-z));
}

template<bool F32> __device__ __forceinline__ float ldg1(const void* p, size_t i) {
    if (F32) return ((const float*)p)[i];
    return bf2f(((const u16*)p)[i]);
}
template<bool F32> __device__ __forceinline__ void stg1(void* p, size_t i, float v) {
    if (F32) ((float*)p)[i] = v;
    else     ((u16*)p)[i] = f2bf(v);
}
__device__ __forceinline__ float ldany(const void* p, size_t i, bool f32) {
    return f32 ? ((const float*)p)[i] : bf2f(((const u16*)p)[i]);
}
// wave-level LDS fence
__device__ __forceinline__ void wave_lds_fence() {
    __builtin_amdgcn_wave_barrier();
    __builtin_amdgcn_s_waitcnt(0xc07f);   // lgkmcnt(0) only
    __builtin_amdgcn_wave_barrier();
}

// ---------------------------------------------------------------------------
// Fused preprocessing: dtype detect + cvt + fragment-linear blockw + dst hist.
// ---------------------------------------------------------------------------
struct CvtArgs {
    const void* src[8];
    u64 dstoff[8];
    int n[8];
};
struct BwArgs {
    const void* We1; const void* We2; const void* Wv; const void* Wa;
    const void* Wc;  const void* Wo;  const void* Wn1; const void* Wn2;
    const void* Wf1; const void* Wf2;
    u64 b1, b2, b3, b4, b5, b6, b7, b8;
};

__global__ __launch_bounds__(256)
void preproc_kernel(const void* hsrc, int* flag, char* ws, CvtArgs args, BwArgs bwa,
                    const int* __restrict__ dstp, int* __restrict__ cnt)
{
    __shared__ float red[256];
    __shared__ int sflag;
    const int t = threadIdx.x;
    {
        const u16* p = (const u16*)hsrc;
        float mx = 0.f;
        for (int i = 0; i < 8; i++) {
            int idx = (t * 8 + i) * 97;
            float v = fabsf(bf2f(p[idx * 2]));
            mx = fmaxf(mx, v);
        }
        red[t] = mx;
        __syncthreads();
        for (int s = 128; s > 0; s >>= 1) {
            if (t < s) red[t] = fmaxf(red[t], red[t + s]);
            __syncthreads();
        }
        if (t == 0) {
            sflag = (red[0] > 1e10f || red[0] == 0.f) ? 1 : 0;
            if (blockIdx.x == 0) flag[0] = sflag;
        }
        __syncthreads();
    }
    const bool f32 = (sflag != 0);
    const int g = blockIdx.x * 256 + t;
    const int stride = gridDim.x * 256;

    // ---- dst histogram for counting sort ----
    for (int i = g; i < N_EDGES; i += stride)
        atomicAdd(&cnt[dstp[i]], 1);

    // ---- cvt: biases + h + y ----
    for (int ten = 0; ten < 8; ten++) {
        const void* s = args.src[ten];
        u16* d = (u16*)(ws + args.dstoff[ten]);
        const int n = args.n[ten];
        if (f32) {
            const float* sf = (const float*)s;
            for (int i = g; i < n; i += stride) d[i] = f2bf(sf[i]);
        } else {
            const u16* su = (const u16*)s;
            for (int i = g; i < n; i += stride) d[i] = su[i];
        }
    }

    // ---- fragment-linear blocked weights ----
    u16* b1 = (u16*)(ws + bwa.b1);
    u16* b2 = (u16*)(ws + bwa.b2);
    u16* b3 = (u16*)(ws + bwa.b3);
    u16* b4 = (u16*)(ws + bwa.b4);
    u16* b5 = (u16*)(ws + bwa.b5);
    u16* b6 = (u16*)(ws + bwa.b6);
    u16* b7 = (u16*)(ws + bwa.b7);
    u16* b8 = (u16*)(ws + bwa.b8);
    // We1P: [5c][2ks][10nt] tiles, K=320 logical (k==273 -> dup row 256)
    for (int i = g; i < 5*2*10*512; i += stride) {
        int tt = i >> 9, r = i & 511, l = r >> 3, j = r & 7;
        int c = tt / 20, ks = (tt / 10) % 2, nt = tt % 10;
        int k = c*64 + ks*32 + (l >> 4)*8 + j;
        int n = nt*16 + (l & 15);
        float v = 0.f;
        if (k < MSG_F)      v = ldany(bwa.We1, (size_t)k*INNER + n, f32);
        else if (k == 273)  v = ldany(bwa.We1, (size_t)256*INNER + n, f32);
        b1[i] = f2bf(v);
    }
    // We2P: [5 k5][10 nt], K=160
    for (int i = g; i < 5*10*512; i += stride) {
        int tt = i >> 9, r = i & 511, l = r >> 3, j = r & 7;
        int k5 = tt / 10, nt = tt % 10;
        int k = k5*32 + (l >> 4)*8 + j;
        int n = nt*16 + (l & 15);
        b2[i] = f2bf(ldany(bwa.We2, (size_t)k*INNER + n, f32));
    }
    // W3P: [5 k5][9 nt], K=160; n<128 Wv | n<136 Wa | n==136 Wc | else 0
    for (int i = g; i < 5*9*512; i += stride) {
        int tt = i >> 9, r = i & 511, l = r >> 3, j = r & 7;
        int k5 = tt / 9, nt = tt % 9;
        int k = k5*32 + (l >> 4)*8 + j;
        int n = nt*16 + (l & 15);
        float v = 0.f;
        if (n < 128)       v = ldany(bwa.Wv, (size_t)k*HID + n, f32);
        else if (n < 136)  v = ldany(bwa.Wa, (size_t)k*HEADS + (n-128), f32);
        else if (n == 136) v = ldany(bwa.Wc, (size_t)k, f32);
        b3[i] = f2bf(v);
    }
    // WoP: [4 cks][8 nt], K=128
    for (int i = g; i < 4*8*512; i += stride) {
        int tt = i >> 9, r = i & 511, l = r >> 3, j = r & 7;
        int cks = tt / 8, nt = tt % 8;
        int k = cks*32 + (l >> 4)*8 + j;
        int n = nt*16 + (l & 15);
        b4[i] = f2bf(ldany(bwa.Wo, (size_t)k*HID + n, f32));
    }
    // Wn1P: [4 cks][10 nt], K=128
    for (int i = g; i < 4*10*512; i += stride) {
        int tt = i >> 9, r = i & 511, l = r >> 3, j = r & 7;
        int cks = tt / 10, nt = tt % 10;
        int k = cks*32 + (l >> 4)*8 + j;
        int n = nt*16 + (l & 15);
        b5[i] = f2bf(ldany(bwa.Wn1, (size_t)k*INNER + n, f32));
    }
    // Wn2P: [5 k5][8 nt], K=160
    for (int i = g; i < 5*8*512; i += stride) {
        int tt = i >> 9, r = i & 511, l = r >> 3, j = r & 7;
        int k5 = tt / 8, nt = tt % 8;
        int k = k5*32 + (l >> 4)*8 + j;
        int n = nt*16 + (l & 15);
        b6[i] = f2bf(ldany(bwa.Wn2, (size_t)k*HID + n, f32));
    }
    // Wf1P / Wf2P: [2 ks][16 nt], K=64
    for (int i = g; i < 2*16*512; i += stride) {
        int tt = i >> 9, r = i & 511, l = r >> 3, j = r & 7;
        int ks = tt / 16, nt = tt % 16;
        int k = ks*32 + (l >> 4)*8 + j;
        int n = nt*16 + (l & 15);
        b7[i] = f2bf(ldany(bwa.Wf1, (size_t)k*256 + n, f32));
        b8[i] = f2bf(ldany(bwa.Wf2, (size_t)k*256 + n, f32));
    }
}

// ---------------------------------------------------------------------------
// Counting-sort: exclusive scan of the 25000-bin histogram (single block).
// Thread t owns bins [t*25, t*25+25).
// ---------------------------------------------------------------------------
__global__ __launch_bounds__(1024)
void scan_kernel(const int* __restrict__ cnt, int* __restrict__ cursor)
{
    __shared__ int ssum[1024];
    const int t = threadIdx.x;
    const int base = t * 25;
    int loc[25];
    int s = 0;
    #pragma unroll
    for (int j = 0; j < 25; j++) {
        int i = base + j;
        int v = (i < N_NODES) ? cnt[i] : 0;
        loc[j] = s; s += v;
    }
    ssum[t] = s;
    __syncthreads();
    for (int off = 1; off < 1024; off <<= 1) {
        int v = (t >= off) ? ssum[t - off] : 0;
        __syncthreads();
        ssum[t] += v;
        __syncthreads();
    }
    int offs = (t > 0) ? ssum[t - 1] : 0;
    #pragma unroll
    for (int j = 0; j < 25; j++) {
        int i = base + j;
        if (i < N_NODES) cursor[i] = offs + loc[j];
    }
}

__global__ __launch_bounds__(256)
void scatter_kernel(const int* __restrict__ dstp, int* __restrict__ cursor,
                    int* __restrict__ perm)
{
    int i = blockIdx.x * 256 + threadIdx.x;
    if (i < N_EDGES) {
        int pos = atomicAdd(&cursor[dstp[i]], 1);
        perm[pos] = i;
    }
}

// ---------------------------------------------------------------------------
// MFMA edge kernel over dst-SORTED edges (via perm). The epilogue does a
// per-wave segmented reduction in LDS over the sorted dst runs, so the
// global f32 atomics drop from 16 rows x 139 cols to ~2 runs x 139 cols
// per wave (~8x fewer atomic slots), and accumulation happens in f32.
// ---------------------------------------------------------------------------
template<bool F32>   // applies to coords / a only
__device__ __forceinline__ void edge_body(
    const u16* __restrict__ hbf, const void* coords, const void* a,
    const int* __restrict__ src, const int* __restrict__ dst,
    const int* __restrict__ perm,
    const u16* __restrict__ We1P, const u16* __restrict__ We2P,
    const u16* __restrict__ W3P,
    const u16* __restrict__ cbe1, const u16* __restrict__ cbe2,
    float* __restrict__ den, float* __restrict__ hagg, float* __restrict__ cacc,
    u16* sPool, float* sdiff, float* srad, int* ssrc, int* sdstl, int* sedge)
{
    const int t   = threadIdx.x;
    const int w   = t >> 6;
    const int l   = t & 63;
    const int col = l & 15;
    const int q   = l >> 4;
    const int e0  = blockIdx.x * 64;
    const int l8  = l << 3;

    u16* sF  = sPool;               // [64][360]
    u16* sM1 = sPool;               // [64][168] (aliases sF)
    u16* sM2 = sPool + 64*168;      // [64][168]

    if (t < 64) {
        int e = perm[e0 + t];
        sedge[t] = e;
        int s = src[e], d = dst[e];
        ssrc[t] = s; sdstl[t] = d;
        float dx = ldg1<F32>(coords, (size_t)s*3+0) - ldg1<F32>(coords, (size_t)d*3+0);
        float dy = ldg1<F32>(coords, (size_t)s*3+1) - ldg1<F32>(coords, (size_t)d*3+1);
        float dz = ldg1<F32>(coords, (size_t)s*3+2) - ldg1<F32>(coords, (size_t)d*3+2);
        sdiff[t*4+0] = dx; sdiff[t*4+1] = dy; sdiff[t*4+2] = dz;
        float r2 = dx*dx + dy*dy + dz*dz;
        srad[t] = r2;
        sdiff[t*4+3] = 1.0f / (sqrtf(r2 + 1e-5f) + 1.0f);
    }
    __syncthreads();                                    // B1

    // ---- stage ALL f chunks (4 lanes per edge, pure bf16 copies) ----
    {
        int e = t >> 2, part = t & 3;
        int node_s = ssrc[e], node_d = sdstl[e];
        int ge = sedge[e];
        #pragma unroll
        for (int c = 0; c < 4; c++) {
            int node = (c < 2) ? node_s : node_d;
            int c0 = (c & 1) * 64 + part * 16;
            const uint4* gp = (const uint4*)(hbf + (size_t)node*HID + c0);
            *(uint4*)(&sF[e*360 + c*72 + part*16])     = gp[0];
            *(uint4*)(&sF[e*360 + c*72 + part*16 + 8]) = gp[1];
        }
        if (part < 2) {
            __align__(16) u16 tmp[16];
            #pragma unroll
            for (int j = 0; j < 16; j++) tmp[j] = 0;
            if (part == 0) {
                float r2 = srad[e];
                tmp[0] = f2bf(r2);                           // kc0 = radial hi
                for (int j = 0; j < 15; j++)
                    tmp[1+j] = f2bf(ldg1<F32>(a, (size_t)ge*EDGE_F + j));
            } else {
                tmp[0] = f2bf(ldg1<F32>(a, (size_t)ge*EDGE_F + 15));
                float r2 = srad[e];
                tmp[1] = f2bf(r2 - bf2f(f2bf(r2)));          // kc17 = radial lo
            }
            *(uint4*)(&sF[e*360 + 4*72 + part*16])     = ((uint4*)tmp)[0];
            *(uint4*)(&sF[e*360 + 4*72 + part*16 + 8]) = ((uint4*)tmp)[1];
        }
    }
    __syncthreads();                                    // B2

    // ---- GEMM1: K=288 effective ----
    f32x4 acc1[10];
    #pragma unroll
    for (int nt = 0; nt < 10; nt++) {
        float v = bf2f(cbe1[nt*16 + col]);
        acc1[nt] = (f32x4){v, v, v, v};
    }
    const u16* fbase = &sF[(w*16 + col)*360];
    #pragma unroll
    for (int c = 0; c < 4; c++) {
        #pragma unroll
        for (int ks = 0; ks < 2; ks++) {
            short8 af = *(const short8*)(fbase + c*72 + ks*32 + q*8);
            const u16* B1 = We1P + (((c*2 + ks)*10) << 9) + l8;
            #pragma unroll
            for (int nt = 0; nt < 10; nt++) {
                short8 b = *(const short8*)(B1 + (nt << 9));
                acc1[nt] = __builtin_amdgcn_mfma_f32_16x16x32_bf16(af, b, acc1[nt], 0, 0, 0);
            }
        }
    }
    {   // c=4, ks=0 only
        short8 af = *(const short8*)(fbase + 4*72 + q*8);
        const u16* B1 = We1P + ((8*10) << 9) + l8;
        #pragma unroll
        for (int nt = 0; nt < 10; nt++) {
            short8 b = *(const short8*)(B1 + (nt << 9));
            acc1[nt] = __builtin_amdgcn_mfma_f32_16x16x32_bf16(af, b, acc1[nt], 0, 0, 0);
        }
    }
    __syncthreads();                                    // B3 (sF dead)
    #pragma unroll
    for (int nt = 0; nt < 10; nt++)
        #pragma unroll
        for (int r = 0; r < 4; r++)
            sM1[(w*16 + q*4 + r)*168 + nt*16 + col] = f2bf(silu(acc1[nt][r]));
    __syncthreads();                                    // B4

    // ---- GEMM2: K=160 ----
    f32x4 acc2[10];
    #pragma unroll
    for (int nt = 0; nt < 10; nt++) {
        float v = bf2f(cbe2[nt*16 + col]);
        acc2[nt] = (f32x4){v, v, v, v};
    }
    const u16* m1base = &sM1[(w*16 + col)*168];
    #pragma unroll
    for (int k5 = 0; k5 < 5; k5++) {
        short8 af = *(const short8*)(m1base + k5*32 + q*8);
        const u16* B2 = We2P + ((k5*10) << 9) + l8;
        #pragma unroll
        for (int nt = 0; nt < 10; nt++) {
            short8 b = *(const short8*)(B2 + (nt << 9));
            acc2[nt] = __builtin_amdgcn_mfma_f32_16x16x32_bf16(af, b, acc2[nt], 0, 0, 0);
        }
    }
    #pragma unroll
    for (int nt = 0; nt < 10; nt++)
        #pragma unroll
        for (int r = 0; r < 4; r++)
            sM2[(w*16 + q*4 + r)*168 + nt*16 + col] = f2bf(silu(acc2[nt][r]));
    __syncthreads();                                    // B5

    // ---- GEMM3: N=144, K=160 ----
    f32x4 acc3[9];
    #pragma unroll
    for (int nt = 0; nt < 9; nt++) acc3[nt] = (f32x4){0.f, 0.f, 0.f, 0.f};
    const u16* m2base = &sM2[(w*16 + col)*168];
    #pragma unroll
    for (int k5 = 0; k5 < 5; k5++) {
        short8 af = *(const short8*)(m2base + k5*32 + q*8);
        const u16* B3 = W3P + ((k5*9) << 9) + l8;
        #pragma unroll
        for (int nt = 0; nt < 9; nt++) {
            short8 b = *(const short8*)(B3 + (nt << 9));
            acc3[nt] = __builtin_amdgcn_mfma_f32_16x16x32_bf16(af, b, acc3[nt], 0, 0, 0);
        }
    }
    __syncthreads();                                    // B6 (sM1/sM2 dead -> reuse as f32 scratch)

    // ---- epilogue: per-wave LDS transpose + segmented reduction over runs ----
    float* scr = (float*)(void*)sPool + (size_t)w * 16 * SCR_STRIDE;  // [16][SCR_STRIDE]

    {
        float exv[4] = {0.f, 0.f, 0.f, 0.f};
        if (col < 8) {
            #pragma unroll
            for (int r = 0; r < 4; r++)
                exv[r] = __expf(fminf(fmaxf(acc3[8][r], -30.f), 30.f));
        }
        #pragma unroll
        for (int nt = 0; nt < 8; nt++) {
            float ex0 = __shfl(exv[0], q*16 + nt);
            float ex1 = __shfl(exv[1], q*16 + nt);
            float ex2 = __shfl(exv[2], q*16 + nt);
            float ex3 = __shfl(exv[3], q*16 + nt);
            scr[(q*4 + 0)*SCR_STRIDE + nt*16 + col] = acc3[nt][0] * ex0;
            scr[(q*4 + 1)*SCR_STRIDE + nt*16 + col] = acc3[nt][1] * ex1;
            scr[(q*4 + 2)*SCR_STRIDE + nt*16 + col] = acc3[nt][2] * ex2;
            scr[(q*4 + 3)*SCR_STRIDE + nt*16 + col] = acc3[nt][3] * ex3;
        }
        if (col < 8) {
            #pragma unroll
            for (int r = 0; r < 4; r++)
                scr[(q*4 + r)*SCR_STRIDE + 128 + col] = exv[r];
        }
        if (col == 8) {
            #pragma unroll
            for (int r = 0; r < 4; r++) {
                int idx = w*16 + q*4 + r;
                float invf = sdiff[idx*4 + 3];
                float lc = fminf(fmaxf(acc3[8][r], -1e6f), 1e6f) * invf;
                #pragma unroll
                for (int j = 0; j < 3; j++)
                    scr[(q*4 + r)*SCR_STRIDE + 136 + j] = lc * sdiff[idx*4 + j];
            }
        }
    }
    wave_lds_fence();

    {
        const int rbase = w*16;
        int dsts[16];
        #pragma unroll
        for (int row = 0; row < 16; row++) dsts[row] = sdstl[rbase + row];

        #pragma unroll
        for (int pass = 0; pass < 3; pass++) {
            int c = pass*64 + l;
            bool act = c < 139;
            float accu = 0.f;
            int prevd = dsts[0];
            #pragma unroll
            for (int row = 0; row < 16; row++) {
                int d = dsts[row];
                if (d != prevd) {
                    if (act) {
                        if (c < 128)      atomicAdd(&hagg[(size_t)prevd*HID + c], accu);
                        else if (c < 136) atomicAdd(&den[(size_t)prevd*8 + (c-128)], accu);
                        else              atomicAdd(&cacc[(size_t)prevd*3 + (c-136)], accu);
                    }
                    accu = 0.f; prevd = d;
                }
                if (act) accu += scr[row*SCR_STRIDE + c];
            }
            if (act) {
                if (c < 128)      atomicAdd(&hagg[(size_t)prevd*HID + c], accu);
                else if (c < 136) atomicAdd(&den[(size_t)prevd*8 + (c-128)], accu);
                else              atomicAdd(&cacc[(size_t)prevd*3 + (c-136)], accu);
            }
        }
    }
}

__global__ __launch_bounds__(256, 3)
void edge_kernel(const int* __restrict__ flag,
                 const u16* __restrict__ hbf, const void* coords, const void* a,
                 const int* __restrict__ src, const int* __restrict__ dst,
                 const int* __restrict__ perm,
                 const u16* __restrict__ We1P, const u16* __restrict__ We2P,
                 const u16* __restrict__ W3P,
                 const u16* __restrict__ cbe1, const u16* __restrict__ cbe2,
                 float* __restrict__ den, float* __restrict__ hagg,
                 float* __restrict__ cacc)
{
    __shared__ __align__(16) u16 sPool[64*360];   // 46080 B (>= 4*16*SCR_STRIDE*4)
    __shared__ float sdiff[64*4];
    __shared__ float srad[64];
    __shared__ int   ssrc[64];
    __shared__ int   sdstl[64];
    __shared__ int   sedge[64];
    if (*flag)
        edge_body<true>(hbf, coords, a, src, dst, perm, We1P, We2P, W3P, cbe1, cbe2,
                        den, hagg, cacc, sPool, sdiff, srad, ssrc, sdstl, sedge);
    else
        edge_body<false>(hbf, coords, a, src, dst, perm, We1P, We2P, W3P, cbe1, cbe2,
                         den, hagg, cacc, sPool, sdiff, srad, ssrc, sdstl, sedge);
}

// ---------------------------------------------------------------------------
// Barrier-free fused MFMA node kernel, fragment-linear B reads. (f32 den/hagg)
// ---------------------------------------------------------------------------
template<bool F32>   // applies to res / coords / out
__device__ __forceinline__ void node_body(
    const u16* __restrict__ hbf, const void* res, const void* coords,
    const u16* __restrict__ ybf,
    const float* __restrict__ den, const float* __restrict__ hagg,
    const float* __restrict__ cacc,
    const u16* __restrict__ WoP, const u16* __restrict__ Wn1P,
    const u16* __restrict__ Wn2P, const u16* __restrict__ Wf1P,
    const u16* __restrict__ Wf2P,
    const u16* __restrict__ cbn1, const u16* __restrict__ cbn2,
    const u16* __restrict__ cbf1, const u16* __restrict__ cbf2,
    void* out, u16* sScr)
{
    const int t = threadIdx.x;
    const int w = t >> 6, l = t & 63, col = l & 15, q = l >> 4;
    const int nodew = blockIdx.x * 64 + w * 16;
    const int mynode = nodew + col;
    const bool okA = mynode < N_NODES;
    const int l8 = l << 3;
    u16* sc = sScr + w * 16 * 168;

    int gm[4]; bool okC[4];
    #pragma unroll
    for (int r = 0; r < 4; r++) { gm[r] = nodew + q*4 + r; okC[r] = gm[r] < N_NODES; }

    f32x4 aF2[8];
    #pragma unroll
    for (int nt = 0; nt < 8; nt++) aF2[nt] = (f32x4){0.f,0.f,0.f,0.f};
    #pragma unroll
    for (int c = 0; c < 2; c++) {
        #pragma unroll
        for (int ks = 0; ks < 2; ks++) {
            const int kbase = c*64 + ks*32 + q*8;
            union { u16 s[8]; short8 v; } u;
            if (okA) {
                float dd = den[(size_t)mynode*8 + (kbase >> 4)];
                float inv = dd > 0.f ? 1.f/dd : 0.f;
                const float4* gp = (const float4*)(hagg + (size_t)mynode*HID + kbase);
                float4 v0 = gp[0], v1 = gp[1];
                u.s[0]=f2bf(v0.x*inv); u.s[1]=f2bf(v0.y*inv); u.s[2]=f2bf(v0.z*inv); u.s[3]=f2bf(v0.w*inv);
                u.s[4]=f2bf(v1.x*inv); u.s[5]=f2bf(v1.y*inv); u.s[6]=f2bf(v1.z*inv); u.s[7]=f2bf(v1.w*inv);
            } else {
                #pragma unroll
                for (int j = 0; j < 8; j++) u.s[j] = 0;
            }
            const u16* B = WoP + (((c*2 + ks)*8) << 9) + l8;
            #pragma unroll
            for (int nt = 0; nt < 8; nt++) {
                short8 b = *(const short8*)(B + (nt << 9));
                aF2[nt] = __builtin_amdgcn_mfma_f32_16x16x32_bf16(u.v, b, aF2[nt], 0, 0, 0);
            }
        }
    }

    f32x4 aFl[16];
    #pragma unroll
    for (int nt = 0; nt < 16; nt++) {
        float v = bf2f(cbf1[nt*16 + col]);
        aFl[nt] = (f32x4){v,v,v,v};
    }
    #pragma unroll
    for (int ks = 0; ks < 2; ks++) {
        short8 af;
        if (okA) af = *(const short8*)(ybf + (size_t)mynode*ADY + ks*32 + q*8);
        else { union { u16 s[8]; short8 v; } z; for (int j=0;j<8;j++) z.s[j]=0; af = z.v; }
        const u16* B = Wf1P + ((ks*16) << 9) + l8;
        #pragma unroll
        for (int nt = 0; nt < 16; nt++) {
            short8 b = *(const short8*)(B + (nt << 9));
            aFl[nt] = __builtin_amdgcn_mfma_f32_16x16x32_bf16(af, b, aFl[nt], 0, 0, 0);
        }
    }

    float h1c[8][4], r1c[8][4];
    {
        float xv[8][4], s[4], ss[4];
        #pragma unroll
        for (int r = 0; r < 4; r++) { s[r] = 0.f; ss[r] = 0.f; }
        #pragma unroll
        for (int nt = 0; nt < 8; nt++)
            #pragma unroll
            for (int r = 0; r < 4; r++) {
                float hv = okC[r] ? bf2f(hbf[(size_t)gm[r]*HID + nt*16 + col]) : 0.f;
                float x = hv + aF2[nt][r];
                xv[nt][r] = x; s[r] += x; ss[r] += x*x;
            }
        #pragma unroll
        for (int r = 0; r < 4; r++)
            for (int off = 1; off <= 8; off <<= 1) {
                s[r]  += __shfl_xor(s[r], off);
                ss[r] += __shfl_xor(ss[r], off);
            }
        #pragma unroll
        for (int r = 0; r < 4; r++) {
            float mu = s[r] * (1.f/128.f);
            float var = ss[r] * (1.f/128.f) - mu*mu;
            float rs = rsqrtf(fmaxf(var, 0.f) + 1e-5f);
            #pragma unroll
            for (int nt = 0; nt < 8; nt++) {
                float h1 = (xv[nt][r]-mu)*rs*(1.f+aFl[nt][r]) + aFl[nt+8][r];
                h1c[nt][r] = h1;
                float rv = okC[r] ? ldg1<F32>(res, (size_t)gm[r]*HID + nt*16 + col) : 0.f;
                r1c[nt][r] = rv + aF2[nt][r];
                sc[(q*4 + r)*168 + nt*16 + col] = f2bf(h1);
            }
        }
    }
    wave_lds_fence();

    f32x4 aT[10];
    #pragma unroll
    for (int nt = 0; nt < 10; nt++) {
        float v = bf2f(cbn1[nt*16 + col]);
        aT[nt] = (f32x4){v,v,v,v};
    }
    #pragma unroll
    for (int c = 0; c < 2; c++) {
        #pragma unroll
        for (int ks = 0; ks < 2; ks++) {
            short8 af = *(const short8*)(sc + col*168 + c*64 + ks*32 + q*8);
            const u16* B = Wn1P + (((c*2 + ks)*10) << 9) + l8;
            #pragma unroll
            for (int nt = 0; nt < 10; nt++) {
                short8 b = *(const short8*)(B + (nt << 9));
                aT[nt] = __builtin_amdgcn_mfma_f32_16x16x32_bf16(af, b, aT[nt], 0, 0, 0);
            }
        }
    }
    wave_lds_fence();
    #pragma unroll
    for (int nt = 0; nt < 10; nt++)
        #pragma unroll
        for (int r = 0; r < 4; r++)
            sc[(q*4 + r)*168 + nt*16 + col] = f2bf(silu(aT[nt][r]));
    wave_lds_fence();

    f32x4 aF3[8];
    #pragma unroll
    for (int nt = 0; nt < 8; nt++) {
        float v = bf2f(cbn2[nt*16 + col]);
        aF3[nt] = (f32x4){v,v,v,v};
    }
    #pragma unroll
    for (int k5 = 0; k5 < 5; k5++) {
        short8 af = *(const short8*)(sc + col*168 + k5*32 + q*8);
        const u16* B = Wn2P + ((k5*8) << 9) + l8;
        #pragma unroll
        for (int nt = 0; nt < 8; nt++) {
            short8 b = *(const short8*)(B + (nt << 9));
            aF3[nt] = __builtin_amdgcn_mfma_f32_16x16x32_bf16(af, b, aF3[nt], 0, 0, 0);
        }
    }

    #pragma unroll
    for (int nt = 0; nt < 16; nt++) {
        float v = bf2f(cbf2[nt*16 + col]);
        aFl[nt] = (f32x4){v,v,v,v};
    }
    #pragma unroll
    for (int ks = 0; ks < 2; ks++) {
        short8 af;
        if (okA) af = *(const short8*)(ybf + (size_t)mynode*ADY + ks*32 + q*8);
        else { union { u16 s[8]; short8 v; } z; for (int j=0;j<8;j++) z.s[j]=0; af = z.v; }
        const u16* B = Wf2P + ((ks*16) << 9) + l8;
        #pragma unroll
        for (int nt = 0; nt < 16; nt++) {
            short8 b = *(const short8*)(B + (nt << 9));
            aFl[nt] = __builtin_amdgcn_mfma_f32_16x16x32_bf16(af, b, aFl[nt], 0, 0, 0);
        }
    }

    {
        float xv[8][4], s[4], ss[4];
        #pragma unroll
        for (int r = 0; r < 4; r++) { s[r] = 0.f; ss[r] = 0.f; }
        #pragma unroll
        for (int nt = 0; nt < 8; nt++)
            #pragma unroll
            for (int r = 0; r < 4; r++) {
                float x = h1c[nt][r] + aF3[nt][r];
                xv[nt][r] = x; s[r] += x; ss[r] += x*x;
            }
        #pragma unroll
        for (int r = 0; r < 4; r++)
            for (int off = 1; off <= 8; off <<= 1) {
                s[r]  += __shfl_xor(s[r], off);
                ss[r] += __shfl_xor(ss[r], off);
            }
        #pragma unroll
        for (int r = 0; r < 4; r++) {
            float mu = s[r] * (1.f/128.f);
            float var = ss[r] * (1.f/128.f) - mu*mu;
            float rs = rsqrtf(fmaxf(var, 0.f) + 1e-5f);
            if (okC[r]) {
                #pragma unroll
                for (int nt = 0; nt < 8; nt++) {
                    int n = nt*16 + col;
                    float h2 = (xv[nt][r]-mu)*rs*(1.f+aFl[nt][r]) + aFl[nt+8][r];
                    stg1<F32>(out, (size_t)gm[r]*HID + n, h2);
                    stg1<F32>(out, (size_t)OUT_RES + (size_t)gm[r]*HID + n,
                              r1c[nt][r] + aF3[nt][r]);
                }
            }
        }
    }

    if (q == 0 && okA) {
        #pragma unroll
        for (int j = 0; j < 3; j++)
            stg1<F32>(out, (size_t)OUT_CRD + (size_t)mynode*3 + j,
                      ldg1<F32>(coords, (size_t)mynode*3 + j) + cacc[(size_t)mynode*3 + j]);
    }
}

__global__ __launch_bounds__(256, 2)
void node_kernel(const int* __restrict__ flag,
                 const u16* __restrict__ hbf, const void* res, const void* coords,
                 const u16* __restrict__ ybf,
                 const float* __restrict__ den, const float* __restrict__ hagg,
                 const float* __restrict__ cacc,
                 const u16* __restrict__ WoP, const u16* __restrict__ Wn1P,
                 const u16* __restrict__ Wn2P, const u16* __restrict__ Wf1P,
                 const u16* __restrict__ Wf2P,
                 const u16* __restrict__ cbn1, const u16* __restrict__ cbn2,
                 const u16* __restrict__ cbf1, const u16* __restrict__ cbf2,
                 void* out)
{
    __shared__ __align__(16) u16 sScr[4 * 16 * 168];
    if (*flag)
        node_body<true>(hbf, res, coords, ybf, den, hagg, cacc, WoP, Wn1P, Wn2P,
                        Wf1P, Wf2P, cbn1, cbn2, cbf1, cbf2, out, sScr);
    else
        node_body<false>(hbf, res, coords, ybf, den, hagg, cacc, WoP, Wn1P, Wn2P,
                         Wf1P, Wf2P, cbn1, cbn2, cbf1, cbf2, out, sScr);
}

// ---------------------------------------------------------------------------
extern "C" void kernel_launch(void* const* d_in, const int* in_sizes, int n_in,
                              void* d_out, int out_size, void* d_ws, size_t ws_size,
                              hipStream_t stream)
{
    const void* h      = d_in[0];
    const void* coords = d_in[1];
    const void* a      = d_in[2];
    const void* y      = d_in[3];
    const void* res    = d_in[4];
    const int* src     = (const int*)d_in[5];
    const int* dst     = (const int*)d_in[6];

    char* ws = (char*)d_ws;
    int*   flag   = (int*)(ws + FLAG_OFF);
    float* den    = (float*)(ws + DEN_OFF);
    float* cacc   = (float*)(ws + CACC_OFF);
    float* hagg   = (float*)(ws + HAGG_OFF);
    int*   cnt    = (int*)(ws + CNT_OFF);
    int*   cursor = (int*)(ws + CUR_OFF);
    int*   perm   = (int*)(ws + PERM_OFF);
    u16*   hbf    = (u16*)(ws + HBF_OFF);
    u16*   ybf    = (u16*)(ws + YBF_OFF);

    // convert list: 6 biases + h + y
    CvtArgs args;
    const int cvtn[8]   = {160, 160, 160, 128, 256, 256, N_NODES*HID, N_NODES*ADY};
    const int cvtsrc[8] = {8, 10, 16, 18, 20, 22, 0, 3};
    u64 boff[8];
    u64 bo = BIAS_OFF;
    for (int i = 0; i < 6; i++) {
        boff[i] = bo;
        bo += ((u64)cvtn[i] * 2 + 15) & ~(u64)15;
    }
    boff[6] = HBF_OFF;
    boff[7] = YBF_OFF;
    for (int i = 0; i < 8; i++) {
        args.src[i] = d_in[cvtsrc[i]];
        args.dstoff[i] = boff[i];
        args.n[i] = cvtn[i];
    }
    const u16* cbe1 = (const u16*)(ws + boff[0]);
    const u16* cbe2 = (const u16*)(ws + boff[1]);
    const u16* cbn1 = (const u16*)(ws + boff[2]);
    const u16* cbn2 = (const u16*)(ws + boff[3]);
    const u16* cbf1 = (const u16*)(ws + boff[4]);
    const u16* cbf2 = (const u16*)(ws + boff[5]);

    // fragment-linear blocked weights
    BwArgs bwa;
    bwa.We1 = d_in[7];  bwa.We2 = d_in[9];  bwa.Wv = d_in[12]; bwa.Wa = d_in[13];
    bwa.Wc  = d_in[11]; bwa.Wo  = d_in[14]; bwa.Wn1 = d_in[15]; bwa.Wn2 = d_in[17];
    bwa.Wf1 = d_in[19]; bwa.Wf2 = d_in[21];
    bwa.b1 = BW_OFF;
    bwa.b2 = bwa.b1 + (u64)5*2*10*512*2;   // 102400 B
    bwa.b3 = bwa.b2 + (u64)5*10*512*2;     //  51200 B
    bwa.b4 = bwa.b3 + (u64)5*9*512*2;      //  46080 B
    bwa.b5 = bwa.b4 + (u64)4*8*512*2;      //  32768 B
    bwa.b6 = bwa.b5 + (u64)4*10*512*2;     //  40960 B
    bwa.b7 = bwa.b6 + (u64)5*8*512*2;      //  40960 B
    bwa.b8 = bwa.b7 + (u64)2*16*512*2;     //  32768 B
    const u16* We1P = (const u16*)(ws + bwa.b1);
    const u16* We2P = (const u16*)(ws + bwa.b2);
    const u16* W3P  = (const u16*)(ws + bwa.b3);
    const u16* WoP  = (const u16*)(ws + bwa.b4);
    const u16* Wn1P = (const u16*)(ws + bwa.b5);
    const u16* Wn2P = (const u16*)(ws + bwa.b6);
    const u16* Wf1P = (const u16*)(ws + bwa.b7);
    const u16* Wf2P = (const u16*)(ws + bwa.b8);

    hipMemsetAsync(d_ws, 0, MEMSET_BYTES, stream);

    preproc_kernel<<<256, 256, 0, stream>>>(h, flag, ws, args, bwa, dst, cnt);

    scan_kernel<<<1, 1024, 0, stream>>>(cnt, cursor);

    scatter_kernel<<<(N_EDGES + 255)/256, 256, 0, stream>>>(dst, cursor, perm);

    edge_kernel<<<N_EDGES/64, 256, 0, stream>>>(flag, hbf, coords, a, src, dst, perm,
                                                We1P, We2P, W3P, cbe1, cbe2,
                                                den, hagg, cacc);

    node_kernel<<<(N_NODES + 63)/64, 256, 0, stream>>>(
        flag, hbf, res, coords, ybf, den, hagg, cacc,
        WoP, Wn1P, Wn2P, Wf1P, Wf2P, cbn1, cbn2, cbf1, cbf2, d_out);
}

// Round 4
// 482.079 us; speedup vs baseline: 1.1307x; 1.0952x over previous
//
#include <hip/hip_runtime.h>
#include <math.h>

#define N_NODES 25000
#define N_EDGES 400000
#define HID 128
#define EDGE_F 16
#define ADY 64
#define INNER 160
#define MSG_F 273
#define HEADS 8

// element offsets inside d_out (h2 | coords | res2)
#define OUT_CRD (N_NODES * HID)
#define OUT_RES (N_NODES * (HID + 3))

// ws byte offsets (16-aligned)
#define FLAG_OFF 0
#define DEN_OFF  256                    // f32 [25000][8]   = 800000
#define CACC_OFF 800256                 // f32 [25000][3]   = 300000
#define HAGG_OFF 1100256                // f32 [25000][128] = 12800000
#define CNT_OFF  13900256               // int [25000] histogram
#define CUR_OFF  14000256               // int [25000] scan/cursor
#define PERM_OFF 14100256               // int [400000] dst-sorted edge ids
#define MEMSET_BYTES 14000256           // zero flag..cnt (cursor/perm overwritten)
#define HBF_OFF  15700256               // h as bf16: 6.4 MB
#define YBF_OFF  22100256               // y as bf16: 3.2 MB
#define BIAS_OFF 25300256               // 6 bias tensors, bf16
#define BW_OFF   25302560               // blocked (fragment-linear) weights

// per-wave LDS slice (u16 units): sF 9*512=4608 | sM1 5*512=2560 | sM2 @2560
// | scr (f32) 16*145=2320 f32 = 4640 u16.  slice = 5120 u16 = 10240 B.
#define WSLICE 5120
#define SCR_STRIDE 145

typedef unsigned short u16;
typedef unsigned int u32;
typedef unsigned long long u64;
typedef __attribute__((ext_vector_type(8))) short short8;
typedef __attribute__((ext_vector_type(4))) float f32x4;

__device__ __forceinline__ float bf2f(u16 v) {
    union { u32 u; float f; } x; x.u = ((u32)v) << 16; return x.f;
}
__device__ __forceinline__ u16 f2bf(float f) {
    union { float ff; u32 u; } x; x.ff = f;
    u32 u = x.u;
    u32 rounding = 0x7FFFu + ((u >> 16) & 1u);
    u += rounding;
    return (u16)(u >> 16);
}
__device__ __forceinline__ float silu(float z) {
    z = fminf(fmaxf(z, -30000.f), 30000.f);
    return z / (1.0f + __expf(-z));
}

template<bool F32> __device__ __forceinline__ float ldg1(const void* p, size_t i) {
    if (F32) return ((const float*)p)[i];
    return bf2f(((const u16*)p)[i]);
}
template<bool F32> __device__ __forceinline__ void stg1(void* p, size_t i, float v) {
    if (F32) ((float*)p)[i] = v;
    else     ((u16*)p)[i] = f2bf(v);
}
__device__ __forceinline__ float ldany(const void* p, size_t i, bool f32) {
    return f32 ? ((const float*)p)[i] : bf2f(((const u16*)p)[i]);
}
// wave-level LDS fence (no cross-wave sync needed: all LDS regions wave-private)
__device__ __forceinline__ void wave_lds_fence() {
    __builtin_amdgcn_wave_barrier();
    __builtin_amdgcn_s_waitcnt(0xc07f);   // lgkmcnt(0) only
    __builtin_amdgcn_wave_barrier();
}

// A-fragment address for 16x16x32 bf16 (K-major frag-linear LDS layout):
// element (row lr, k) lives at (k>>5)*512 + ((((k&31)>>3)<<4)|lr)*8 + (k&7)
__device__ __forceinline__ int a_addr(int k, int lr) {
    return ((k >> 5) << 9) + (((((k & 31) >> 3) << 4) | lr) << 3) + (k & 7);
}

// ---------------------------------------------------------------------------
// Fused preprocessing: dtype detect + cvt + fragment-linear blockw + dst hist.
// ---------------------------------------------------------------------------
struct CvtArgs {
    const void* src[8];
    u64 dstoff[8];
    int n[8];
};
struct BwArgs {
    const void* We1; const void* We2; const void* Wv; const void* Wa;
    const void* Wc;  const void* Wo;  const void* Wn1; const void* Wn2;
    const void* Wf1; const void* Wf2;
    u64 b1, b2, b3, b4, b5, b6, b7, b8;
};

__global__ __launch_bounds__(256)
void preproc_kernel(const void* hsrc, int* flag, char* ws, CvtArgs args, BwArgs bwa,
                    const int* __restrict__ dstp, int* __restrict__ cnt)
{
    __shared__ float red[256];
    __shared__ int sflag;
    const int t = threadIdx.x;
    {
        const u16* p = (const u16*)hsrc;
        float mx = 0.f;
        for (int i = 0; i < 8; i++) {
            int idx = (t * 8 + i) * 97;
            float v = fabsf(bf2f(p[idx * 2]));
            mx = fmaxf(mx, v);
        }
        red[t] = mx;
        __syncthreads();
        for (int s = 128; s > 0; s >>= 1) {
            if (t < s) red[t] = fmaxf(red[t], red[t + s]);
            __syncthreads();
        }
        if (t == 0) {
            sflag = (red[0] > 1e10f || red[0] == 0.f) ? 1 : 0;
            if (blockIdx.x == 0) flag[0] = sflag;
        }
        __syncthreads();
    }
    const bool f32 = (sflag != 0);
    const int g = blockIdx.x * 256 + t;
    const int stride = gridDim.x * 256;

    // ---- dst histogram for counting sort ----
    for (int i = g; i < N_EDGES; i += stride)
        atomicAdd(&cnt[dstp[i]], 1);

    // ---- cvt: biases + h + y ----
    for (int ten = 0; ten < 8; ten++) {
        const void* s = args.src[ten];
        u16* d = (u16*)(ws + args.dstoff[ten]);
        const int n = args.n[ten];
        if (f32) {
            const float* sf = (const float*)s;
            for (int i = g; i < n; i += stride) d[i] = f2bf(sf[i]);
        } else {
            const u16* su = (const u16*)s;
            for (int i = g; i < n; i += stride) d[i] = su[i];
        }
    }

    // ---- fragment-linear blocked weights ----
    u16* b1 = (u16*)(ws + bwa.b1);
    u16* b2 = (u16*)(ws + bwa.b2);
    u16* b3 = (u16*)(ws + bwa.b3);
    u16* b4 = (u16*)(ws + bwa.b4);
    u16* b5 = (u16*)(ws + bwa.b5);
    u16* b6 = (u16*)(ws + bwa.b6);
    u16* b7 = (u16*)(ws + bwa.b7);
    u16* b8 = (u16*)(ws + bwa.b8);
    // We1P: [5c][2ks][10nt] tiles, K=320 logical (k==273 -> dup row 256)
    for (int i = g; i < 5*2*10*512; i += stride) {
        int tt = i >> 9, r = i & 511, l = r >> 3, j = r & 7;
        int c = tt / 20, ks = (tt / 10) % 2, nt = tt % 10;
        int k = c*64 + ks*32 + (l >> 4)*8 + j;
        int n = nt*16 + (l & 15);
        float v = 0.f;
        if (k < MSG_F)      v = ldany(bwa.We1, (size_t)k*INNER + n, f32);
        else if (k == 273)  v = ldany(bwa.We1, (size_t)256*INNER + n, f32);
        b1[i] = f2bf(v);
    }
    // We2P: [5 k5][10 nt], K=160
    for (int i = g; i < 5*10*512; i += stride) {
        int tt = i >> 9, r = i & 511, l = r >> 3, j = r & 7;
        int k5 = tt / 10, nt = tt % 10;
        int k = k5*32 + (l >> 4)*8 + j;
        int n = nt*16 + (l & 15);
        b2[i] = f2bf(ldany(bwa.We2, (size_t)k*INNER + n, f32));
    }
    // W3P: [5 k5][9 nt], K=160; n<128 Wv | n<136 Wa | n==136 Wc | else 0
    for (int i = g; i < 5*9*512; i += stride) {
        int tt = i >> 9, r = i & 511, l = r >> 3, j = r & 7;
        int k5 = tt / 9, nt = tt % 9;
        int k = k5*32 + (l >> 4)*8 + j;
        int n = nt*16 + (l & 15);
        float v = 0.f;
        if (n < 128)       v = ldany(bwa.Wv, (size_t)k*HID + n, f32);
        else if (n < 136)  v = ldany(bwa.Wa, (size_t)k*HEADS + (n-128), f32);
        else if (n == 136) v = ldany(bwa.Wc, (size_t)k, f32);
        b3[i] = f2bf(v);
    }
    // WoP: [4 cks][8 nt], K=128
    for (int i = g; i < 4*8*512; i += stride) {
        int tt = i >> 9, r = i & 511, l = r >> 3, j = r & 7;
        int cks = tt / 8, nt = tt % 8;
        int k = cks*32 + (l >> 4)*8 + j;
        int n = nt*16 + (l & 15);
        b4[i] = f2bf(ldany(bwa.Wo, (size_t)k*HID + n, f32));
    }
    // Wn1P: [4 cks][10 nt], K=128
    for (int i = g; i < 4*10*512; i += stride) {
        int tt = i >> 9, r = i & 511, l = r >> 3, j = r & 7;
        int cks = tt / 10, nt = tt % 10;
        int k = cks*32 + (l >> 4)*8 + j;
        int n = nt*16 + (l & 15);
        b5[i] = f2bf(ldany(bwa.Wn1, (size_t)k*INNER + n, f32));
    }
    // Wn2P: [5 k5][8 nt], K=160
    for (int i = g; i < 5*8*512; i += stride) {
        int tt = i >> 9, r = i & 511, l = r >> 3, j = r & 7;
        int k5 = tt / 8, nt = tt % 8;
        int k = k5*32 + (l >> 4)*8 + j;
        int n = nt*16 + (l & 15);
        b6[i] = f2bf(ldany(bwa.Wn2, (size_t)k*HID + n, f32));
    }
    // Wf1P / Wf2P: [2 ks][16 nt], K=64
    for (int i = g; i < 2*16*512; i += stride) {
        int tt = i >> 9, r = i & 511, l = r >> 3, j = r & 7;
        int ks = tt / 16, nt = tt % 16;
        int k = ks*32 + (l >> 4)*8 + j;
        int n = nt*16 + (l & 15);
        b7[i] = f2bf(ldany(bwa.Wf1, (size_t)k*256 + n, f32));
        b8[i] = f2bf(ldany(bwa.Wf2, (size_t)k*256 + n, f32));
    }
}

// ---------------------------------------------------------------------------
// Counting-sort: exclusive scan of the 25000-bin histogram (single block).
// ---------------------------------------------------------------------------
__global__ __launch_bounds__(1024)
void scan_kernel(const int* __restrict__ cnt, int* __restrict__ cursor)
{
    __shared__ int ssum[1024];
    const int t = threadIdx.x;
    const int base = t * 25;
    int loc[25];
    int s = 0;
    #pragma unroll
    for (int j = 0; j < 25; j++) {
        int i = base + j;
        int v = (i < N_NODES) ? cnt[i] : 0;
        loc[j] = s; s += v;
    }
    ssum[t] = s;
    __syncthreads();
    for (int off = 1; off < 1024; off <<= 1) {
        int v = (t >= off) ? ssum[t - off] : 0;
        __syncthreads();
        ssum[t] += v;
        __syncthreads();
    }
    int offs = (t > 0) ? ssum[t - 1] : 0;
    #pragma unroll
    for (int j = 0; j < 25; j++) {
        int i = base + j;
        if (i < N_NODES) cursor[i] = offs + loc[j];
    }
}

__global__ __launch_bounds__(256)
void scatter_kernel(const int* __restrict__ dstp, int* __restrict__ cursor,
                    int* __restrict__ perm)
{
    int i = blockIdx.x * 256 + threadIdx.x;
    if (i < N_EDGES) {
        int pos = atomicAdd(&cursor[dstp[i]], 1);
        perm[pos] = i;
    }
}

// ---------------------------------------------------------------------------
// Barrier-FREE MFMA edge kernel over dst-sorted edges.
// Each wave owns 16 edges + a private 10240 B LDS slice; all staging, GEMMs,
// and the segmented-reduction epilogue are wave-local (lgkmcnt fences only).
// A-operands stored fragment-linear ([kstep][lane][8]) -> contiguous 1 KB
// wave reads, zero bank conflicts. 40960 B LDS total -> 4 blocks/CU.
// ---------------------------------------------------------------------------
template<bool F32>   // applies to coords / a only
__device__ __forceinline__ void edge_body(
    const u16* __restrict__ hbf, const void* coords, const void* a,
    const int* __restrict__ src, const int* __restrict__ dst,
    const int* __restrict__ perm,
    const u16* __restrict__ We1P, const u16* __restrict__ We2P,
    const u16* __restrict__ W3P,
    const u16* __restrict__ cbe1, const u16* __restrict__ cbe2,
    float* __restrict__ den, float* __restrict__ hagg, float* __restrict__ cacc,
    u16* sPool)
{
    const int t   = threadIdx.x;
    const int w   = t >> 6;
    const int l   = t & 63;
    const int col = l & 15;
    const int q   = l >> 4;
    const int e0  = blockIdx.x * 64;
    const int l8  = l << 3;

    u16* sW = sPool + w * WSLICE;

    // ---- staging: 4 lanes per edge (edge = t>>2, within own wave's tile) ----
    const int r = l >> 2;          // row 0..15 within wave tile
    const int p = t & 3;
    const int ge = perm[e0 + w*16 + r];
    const int s_ = src[ge];
    const int d_ = dst[ge];
    float dx = 0.f, dy = 0.f, dz = 0.f, invf = 0.f, r2 = 0.f;
    if (p < 2) {
        dx = ldg1<F32>(coords, (size_t)s_*3+0) - ldg1<F32>(coords, (size_t)d_*3+0);
        dy = ldg1<F32>(coords, (size_t)s_*3+1) - ldg1<F32>(coords, (size_t)d_*3+1);
        dz = ldg1<F32>(coords, (size_t)s_*3+2) - ldg1<F32>(coords, (size_t)d_*3+2);
        r2 = dx*dx + dy*dy + dz*dz;
        invf = 1.0f / (sqrtf(r2 + 1e-5f) + 1.0f);
    }
    #pragma unroll
    for (int c = 0; c < 4; c++) {
        int node = (c < 2) ? s_ : d_;
        int hcol = (c & 1) * 64 + p * 16;
        const uint4* gp = (const uint4*)(hbf + (size_t)node*HID + hcol);
        int k0 = c*64 + p*16;
        *(uint4*)(sW + a_addr(k0,     r)) = gp[0];
        *(uint4*)(sW + a_addr(k0 + 8, r)) = gp[1];
    }
    if (p < 2) {
        __align__(16) u16 tmp[16];
        #pragma unroll
        for (int j = 0; j < 16; j++) tmp[j] = 0;
        if (p == 0) {
            tmp[0] = f2bf(r2);                               // k=256 radial hi
            for (int j = 0; j < 15; j++)
                tmp[1+j] = f2bf(ldg1<F32>(a, (size_t)ge*EDGE_F + j));
        } else {
            tmp[0] = f2bf(ldg1<F32>(a, (size_t)ge*EDGE_F + 15));
            tmp[1] = f2bf(r2 - bf2f(f2bf(r2)));              // k=273 radial lo
        }
        int k0 = 256 + p*16;
        *(uint4*)(sW + a_addr(k0,     r)) = ((uint4*)tmp)[0];
        *(uint4*)(sW + a_addr(k0 + 8, r)) = ((uint4*)tmp)[1];
    }
    wave_lds_fence();                                   // F1: sF staged

    // ---- GEMM1: K=288 (9 ksteps) ----
    f32x4 acc1[10];
    #pragma unroll
    for (int nt = 0; nt < 10; nt++) {
        float v = bf2f(cbe1[nt*16 + col]);
        acc1[nt] = (f32x4){v, v, v, v};
    }
    #pragma unroll
    for (int kk = 0; kk < 9; kk++) {
        short8 af = *(const short8*)(sW + (kk << 9) + l8);
        const u16* B1 = We1P + ((kk*10) << 9) + l8;
        #pragma unroll
        for (int nt = 0; nt < 10; nt++) {
            short8 b = *(const short8*)(B1 + (nt << 9));
            acc1[nt] = __builtin_amdgcn_mfma_f32_16x16x32_bf16(af, b, acc1[nt], 0, 0, 0);
        }
    }
    wave_lds_fence();                                   // F2a: sF reads done
    #pragma unroll
    for (int nt = 0; nt < 10; nt++)
        #pragma unroll
        for (int rr = 0; rr < 4; rr++)
            sW[a_addr(nt*16 + col, q*4 + rr)] = f2bf(silu(acc1[nt][rr]));
    wave_lds_fence();                                   // F2: sM1 ready

    // ---- GEMM2: K=160 ----
    f32x4 acc2[10];
    #pragma unroll
    for (int nt = 0; nt < 10; nt++) {
        float v = bf2f(cbe2[nt*16 + col]);
        acc2[nt] = (f32x4){v, v, v, v};
    }
    #pragma unroll
    for (int k5 = 0; k5 < 5; k5++) {
        short8 af = *(const short8*)(sW + (k5 << 9) + l8);
        const u16* B2 = We2P + ((k5*10) << 9) + l8;
        #pragma unroll
        for (int nt = 0; nt < 10; nt++) {
            short8 b = *(const short8*)(B2 + (nt << 9));
            acc2[nt] = __builtin_amdgcn_mfma_f32_16x16x32_bf16(af, b, acc2[nt], 0, 0, 0);
        }
    }
    // sM2 at slice offset 2560 (disjoint from sM1 [0,2560)) — no fence needed before writes
    #pragma unroll
    for (int nt = 0; nt < 10; nt++)
        #pragma unroll
        for (int rr = 0; rr < 4; rr++)
            sW[2560 + a_addr(nt*16 + col, q*4 + rr)] = f2bf(silu(acc2[nt][rr]));
    wave_lds_fence();                                   // F3: sM2 ready

    // ---- GEMM3: N=144, K=160 ----
    f32x4 acc3[9];
    #pragma unroll
    for (int nt = 0; nt < 9; nt++) acc3[nt] = (f32x4){0.f, 0.f, 0.f, 0.f};
    #pragma unroll
    for (int k5 = 0; k5 < 5; k5++) {
        short8 af = *(const short8*)(sW + 2560 + (k5 << 9) + l8);
        const u16* B3 = W3P + ((k5*9) << 9) + l8;
        #pragma unroll
        for (int nt = 0; nt < 9; nt++) {
            short8 b = *(const short8*)(B3 + (nt << 9));
            acc3[nt] = __builtin_amdgcn_mfma_f32_16x16x32_bf16(af, b, acc3[nt], 0, 0, 0);
        }
    }
    wave_lds_fence();                                   // F4a: sM2 reads done

    // ---- epilogue: wave-local transpose to f32 scratch + segmented reduce ----
    float* scr = (float*)(void*)sW;                     // [16][SCR_STRIDE] f32

    // per-row metadata via shfl from staging lane (row*4)
    int dsts[16];
    #pragma unroll
    for (int row = 0; row < 16; row++) dsts[row] = __shfl(d_, row << 2);
    float dxv[4], dyv[4], dzv[4], ivv[4];
    #pragma unroll
    for (int rr = 0; rr < 4; rr++) {
        int sl = (q*4 + rr) << 2;
        dxv[rr] = __shfl(dx, sl); dyv[rr] = __shfl(dy, sl);
        dzv[rr] = __shfl(dz, sl); ivv[rr] = __shfl(invf, sl);
    }

    {
        float exv[4] = {0.f, 0.f, 0.f, 0.f};
        if (col < 8) {
            #pragma unroll
            for (int rr = 0; rr < 4; rr++)
                exv[rr] = __expf(fminf(fmaxf(acc3[8][rr], -30.f), 30.f));
        }
        #pragma unroll
        for (int nt = 0; nt < 8; nt++) {
            float ex0 = __shfl(exv[0], q*16 + nt);
            float ex1 = __shfl(exv[1], q*16 + nt);
            float ex2 = __shfl(exv[2], q*16 + nt);
            float ex3 = __shfl(exv[3], q*16 + nt);
            scr[(q*4 + 0)*SCR_STRIDE + nt*16 + col] = acc3[nt][0] * ex0;
            scr[(q*4 + 1)*SCR_STRIDE + nt*16 + col] = acc3[nt][1] * ex1;
            scr[(q*4 + 2)*SCR_STRIDE + nt*16 + col] = acc3[nt][2] * ex2;
            scr[(q*4 + 3)*SCR_STRIDE + nt*16 + col] = acc3[nt][3] * ex3;
        }
        if (col < 8) {
            #pragma unroll
            for (int rr = 0; rr < 4; rr++)
                scr[(q*4 + rr)*SCR_STRIDE + 128 + col] = exv[rr];
        }
        if (col == 8) {
            #pragma unroll
            for (int rr = 0; rr < 4; rr++) {
                float lc = fminf(fmaxf(acc3[8][rr], -1e6f), 1e6f) * ivv[rr];
                scr[(q*4 + rr)*SCR_STRIDE + 136] = lc * dxv[rr];
                scr[(q*4 + rr)*SCR_STRIDE + 137] = lc * dyv[rr];
                scr[(q*4 + rr)*SCR_STRIDE + 138] = lc * dzv[rr];
            }
        }
    }
    wave_lds_fence();                                   // F4: scr ready

    #pragma unroll
    for (int pass = 0; pass < 3; pass++) {
        int c = pass*64 + l;
        bool act = c < 139;
        float accu = 0.f;
        int prevd = dsts[0];
        #pragma unroll
        for (int row = 0; row < 16; row++) {
            int d = dsts[row];
            if (d != prevd) {
                if (act) {
                    if (c < 128)      atomicAdd(&hagg[(size_t)prevd*HID + c], accu);
                    else if (c < 136) atomicAdd(&den[(size_t)prevd*8 + (c-128)], accu);
                    else              atomicAdd(&cacc[(size_t)prevd*3 + (c-136)], accu);
                }
                accu = 0.f; prevd = d;
            }
            if (act) accu += scr[row*SCR_STRIDE + c];
        }
        if (act) {
            if (c < 128)      atomicAdd(&hagg[(size_t)prevd*HID + c], accu);
            else if (c < 136) atomicAdd(&den[(size_t)prevd*8 + (c-128)], accu);
            else              atomicAdd(&cacc[(size_t)prevd*3 + (c-136)], accu);
        }
    }
}

__global__ __launch_bounds__(256, 4)
void edge_kernel(const int* __restrict__ flag,
                 const u16* __restrict__ hbf, const void* coords, const void* a,
                 const int* __restrict__ src, const int* __restrict__ dst,
                 const int* __restrict__ perm,
                 const u16* __restrict__ We1P, const u16* __restrict__ We2P,
                 const u16* __restrict__ W3P,
                 const u16* __restrict__ cbe1, const u16* __restrict__ cbe2,
                 float* __restrict__ den, float* __restrict__ hagg,
                 float* __restrict__ cacc)
{
    __shared__ __align__(16) u16 sPool[4 * WSLICE];   // 40960 B exactly
    if (*flag)
        edge_body<true>(hbf, coords, a, src, dst, perm, We1P, We2P, W3P,
                        cbe1, cbe2, den, hagg, cacc, sPool);
    else
        edge_body<false>(hbf, coords, a, src, dst, perm, We1P, We2P, W3P,
                         cbe1, cbe2, den, hagg, cacc, sPool);
}

// ---------------------------------------------------------------------------
// Barrier-free fused MFMA node kernel, fragment-linear B reads. (f32 den/hagg)
// ---------------------------------------------------------------------------
template<bool F32>   // applies to res / coords / out
__device__ __forceinline__ void node_body(
    const u16* __restrict__ hbf, const void* res, const void* coords,
    const u16* __restrict__ ybf,
    const float* __restrict__ den, const float* __restrict__ hagg,
    const float* __restrict__ cacc,
    const u16* __restrict__ WoP, const u16* __restrict__ Wn1P,
    const u16* __restrict__ Wn2P, const u16* __restrict__ Wf1P,
    const u16* __restrict__ Wf2P,
    const u16* __restrict__ cbn1, const u16* __restrict__ cbn2,
    const u16* __restrict__ cbf1, const u16* __restrict__ cbf2,
    void* out, u16* sScr)
{
    const int t = threadIdx.x;
    const int w = t >> 6, l = t & 63, col = l & 15, q = l >> 4;
    const int nodew = blockIdx.x * 64 + w * 16;
    const int mynode = nodew + col;
    const bool okA = mynode < N_NODES;
    const int l8 = l << 3;
    u16* sc = sScr + w * 16 * 168;

    int gm[4]; bool okC[4];
    #pragma unroll
    for (int r = 0; r < 4; r++) { gm[r] = nodew + q*4 + r; okC[r] = gm[r] < N_NODES; }

    f32x4 aF2[8];
    #pragma unroll
    for (int nt = 0; nt < 8; nt++) aF2[nt] = (f32x4){0.f,0.f,0.f,0.f};
    #pragma unroll
    for (int c = 0; c < 2; c++) {
        #pragma unroll
        for (int ks = 0; ks < 2; ks++) {
            const int kbase = c*64 + ks*32 + q*8;
            union { u16 s[8]; short8 v; } u;
            if (okA) {
                float dd = den[(size_t)mynode*8 + (kbase >> 4)];
                float inv = dd > 0.f ? 1.f/dd : 0.f;
                const float4* gp = (const float4*)(hagg + (size_t)mynode*HID + kbase);
                float4 v0 = gp[0], v1 = gp[1];
                u.s[0]=f2bf(v0.x*inv); u.s[1]=f2bf(v0.y*inv); u.s[2]=f2bf(v0.z*inv); u.s[3]=f2bf(v0.w*inv);
                u.s[4]=f2bf(v1.x*inv); u.s[5]=f2bf(v1.y*inv); u.s[6]=f2bf(v1.z*inv); u.s[7]=f2bf(v1.w*inv);
            } else {
                #pragma unroll
                for (int j = 0; j < 8; j++) u.s[j] = 0;
            }
            const u16* B = WoP + (((c*2 + ks)*8) << 9) + l8;
            #pragma unroll
            for (int nt = 0; nt < 8; nt++) {
                short8 b = *(const short8*)(B + (nt << 9));
                aF2[nt] = __builtin_amdgcn_mfma_f32_16x16x32_bf16(u.v, b, aF2[nt], 0, 0, 0);
            }
        }
    }

    f32x4 aFl[16];
    #pragma unroll
    for (int nt = 0; nt < 16; nt++) {
        float v = bf2f(cbf1[nt*16 + col]);
        aFl[nt] = (f32x4){v,v,v,v};
    }
    #pragma unroll
    for (int ks = 0; ks < 2; ks++) {
        short8 af;
        if (okA) af = *(const short8*)(ybf + (size_t)mynode*ADY + ks*32 + q*8);
        else { union { u16 s[8]; short8 v; } z; for (int j=0;j<8;j++) z.s[j]=0; af = z.v; }
        const u16* B = Wf1P + ((ks*16) << 9) + l8;
        #pragma unroll
        for (int nt = 0; nt < 16; nt++) {
            short8 b = *(const short8*)(B + (nt << 9));
            aFl[nt] = __builtin_amdgcn_mfma_f32_16x16x32_bf16(af, b, aFl[nt], 0, 0, 0);
        }
    }

    float h1c[8][4], r1c[8][4];
    {
        float xv[8][4], s[4], ss[4];
        #pragma unroll
        for (int r = 0; r < 4; r++) { s[r] = 0.f; ss[r] = 0.f; }
        #pragma unroll
        for (int nt = 0; nt < 8; nt++)
            #pragma unroll
            for (int r = 0; r < 4; r++) {
                float hv = okC[r] ? bf2f(hbf[(size_t)gm[r]*HID + nt*16 + col]) : 0.f;
                float x = hv + aF2[nt][r];
                xv[nt][r] = x; s[r] += x; ss[r] += x*x;
            }
        #pragma unroll
        for (int r = 0; r < 4; r++)
            for (int off = 1; off <= 8; off <<= 1) {
                s[r]  += __shfl_xor(s[r], off);
                ss[r] += __shfl_xor(ss[r], off);
            }
        #pragma unroll
        for (int r = 0; r < 4; r++) {
            float mu = s[r] * (1.f/128.f);
            float var = ss[r] * (1.f/128.f) - mu*mu;
            float rs = rsqrtf(fmaxf(var, 0.f) + 1e-5f);
            #pragma unroll
            for (int nt = 0; nt < 8; nt++) {
                float h1 = (xv[nt][r]-mu)*rs*(1.f+aFl[nt][r]) + aFl[nt+8][r];
                h1c[nt][r] = h1;
                float rv = okC[r] ? ldg1<F32>(res, (size_t)gm[r]*HID + nt*16 + col) : 0.f;
                r1c[nt][r] = rv + aF2[nt][r];
                sc[(q*4 + r)*168 + nt*16 + col] = f2bf(h1);
            }
        }
    }
    wave_lds_fence();

    f32x4 aT[10];
    #pragma unroll
    for (int nt = 0; nt < 10; nt++) {
        float v = bf2f(cbn1[nt*16 + col]);
        aT[nt] = (f32x4){v,v,v,v};
    }
    #pragma unroll
    for (int c = 0; c < 2; c++) {
        #pragma unroll
        for (int ks = 0; ks < 2; ks++) {
            short8 af = *(const short8*)(sc + col*168 + c*64 + ks*32 + q*8);
            const u16* B = Wn1P + (((c*2 + ks)*10) << 9) + l8;
            #pragma unroll
            for (int nt = 0; nt < 10; nt++) {
                short8 b = *(const short8*)(B + (nt << 9));
                aT[nt] = __builtin_amdgcn_mfma_f32_16x16x32_bf16(af, b, aT[nt], 0, 0, 0);
            }
        }
    }
    wave_lds_fence();
    #pragma unroll
    for (int nt = 0; nt < 10; nt++)
        #pragma unroll
        for (int r = 0; r < 4; r++)
            sc[(q*4 + r)*168 + nt*16 + col] = f2bf(silu(aT[nt][r]));
    wave_lds_fence();

    f32x4 aF3[8];
    #pragma unroll
    for (int nt = 0; nt < 8; nt++) {
        float v = bf2f(cbn2[nt*16 + col]);
        aF3[nt] = (f32x4){v,v,v,v};
    }
    #pragma unroll
    for (int k5 = 0; k5 < 5; k5++) {
        short8 af = *(const short8*)(sc + col*168 + k5*32 + q*8);
        const u16* B = Wn2P + ((k5*8) << 9) + l8;
        #pragma unroll
        for (int nt = 0; nt < 8; nt++) {
            short8 b = *(const short8*)(B + (nt << 9));
            aF3[nt] = __builtin_amdgcn_mfma_f32_16x16x32_bf16(af, b, aF3[nt], 0, 0, 0);
        }
    }

    #pragma unroll
    for (int nt = 0; nt < 16; nt++) {
        float v = bf2f(cbf2[nt*16 + col]);
        aFl[nt] = (f32x4){v,v,v,v};
    }
    #pragma unroll
    for (int ks = 0; ks < 2; ks++) {
        short8 af;
        if (okA) af = *(const short8*)(ybf + (size_t)mynode*ADY + ks*32 + q*8);
        else { union { u16 s[8]; short8 v; } z; for (int j=0;j<8;j++) z.s[j]=0; af = z.v; }
        const u16* B = Wf2P + ((ks*16) << 9) + l8;
        #pragma unroll
        for (int nt = 0; nt < 16; nt++) {
            short8 b = *(const short8*)(B + (nt << 9));
            aFl[nt] = __builtin_amdgcn_mfma_f32_16x16x32_bf16(af, b, aFl[nt], 0, 0, 0);
        }
    }

    {
        float xv[8][4], s[4], ss[4];
        #pragma unroll
        for (int r = 0; r < 4; r++) { s[r] = 0.f; ss[r] = 0.f; }
        #pragma unroll
        for (int nt = 0; nt < 8; nt++)
            #pragma unroll
            for (int r = 0; r < 4; r++) {
                float x = h1c[nt][r] + aF3[nt][r];
                xv[nt][r] = x; s[r] += x; ss[r] += x*x;
            }
        #pragma unroll
        for (int r = 0; r < 4; r++)
            for (int off = 1; off <= 8; off <<= 1) {
                s[r]  += __shfl_xor(s[r], off);
                ss[r] += __shfl_xor(ss[r], off);
            }
        #pragma unroll
        for (int r = 0; r < 4; r++) {
            float mu = s[r] * (1.f/128.f);
            float var = ss[r] * (1.f/128.f) - mu*mu;
            float rs = rsqrtf(fmaxf(var, 0.f) + 1e-5f);
            if (okC[r]) {
                #pragma unroll
                for (int nt = 0; nt < 8; nt++) {
                    int n = nt*16 + col;
                    float h2 = (xv[nt][r]-mu)*rs*(1.f+aFl[nt][r]) + aFl[nt+8][r];
                    stg1<F32>(out, (size_t)gm[r]*HID + n, h2);
                    stg1<F32>(out, (size_t)OUT_RES + (size_t)gm[r]*HID + n,
                              r1c[nt][r] + aF3[nt][r]);
                }
            }
        }
    }

    if (q == 0 && okA) {
        #pragma unroll
        for (int j = 0; j < 3; j++)
            stg1<F32>(out, (size_t)OUT_CRD + (size_t)mynode*3 + j,
                      ldg1<F32>(coords, (size_t)mynode*3 + j) + cacc[(size_t)mynode*3 + j]);
    }
}

__global__ __launch_bounds__(256, 2)
void node_kernel(const int* __restrict__ flag,
                 const u16* __restrict__ hbf, const void* res, const void* coords,
                 const u16* __restrict__ ybf,
                 const float* __restrict__ den, const float* __restrict__ hagg,
                 const float* __restrict__ cacc,
                 const u16* __restrict__ WoP, const u16* __restrict__ Wn1P,
                 const u16* __restrict__ Wn2P, const u16* __restrict__ Wf1P,
                 const u16* __restrict__ Wf2P,
                 const u16* __restrict__ cbn1, const u16* __restrict__ cbn2,
                 const u16* __restrict__ cbf1, const u16* __restrict__ cbf2,
                 void* out)
{
    __shared__ __align__(16) u16 sScr[4 * 16 * 168];
    if (*flag)
        node_body<true>(hbf, res, coords, ybf, den, hagg, cacc, WoP, Wn1P, Wn2P,
                        Wf1P, Wf2P, cbn1, cbn2, cbf1, cbf2, out, sScr);
    else
        node_body<false>(hbf, res, coords, ybf, den, hagg, cacc, WoP, Wn1P, Wn2P,
                         Wf1P, Wf2P, cbn1, cbn2, cbf1, cbf2, out, sScr);
}

// ---------------------------------------------------------------------------
extern "C" void kernel_launch(void* const* d_in, const int* in_sizes, int n_in,
                              void* d_out, int out_size, void* d_ws, size_t ws_size,
                              hipStream_t stream)
{
    const void* h      = d_in[0];
    const void* coords = d_in[1];
    const void* a      = d_in[2];
    const void* y      = d_in[3];
    const void* res    = d_in[4];
    const int* src     = (const int*)d_in[5];
    const int* dst     = (const int*)d_in[6];

    char* ws = (char*)d_ws;
    int*   flag   = (int*)(ws + FLAG_OFF);
    float* den    = (float*)(ws + DEN_OFF);
    float* cacc   = (float*)(ws + CACC_OFF);
    float* hagg   = (float*)(ws + HAGG_OFF);
    int*   cnt    = (int*)(ws + CNT_OFF);
    int*   cursor = (int*)(ws + CUR_OFF);
    int*   perm   = (int*)(ws + PERM_OFF);
    u16*   hbf    = (u16*)(ws + HBF_OFF);
    u16*   ybf    = (u16*)(ws + YBF_OFF);

    // convert list: 6 biases + h + y
    CvtArgs args;
    const int cvtn[8]   = {160, 160, 160, 128, 256, 256, N_NODES*HID, N_NODES*ADY};
    const int cvtsrc[8] = {8, 10, 16, 18, 20, 22, 0, 3};
    u64 boff[8];
    u64 bo = BIAS_OFF;
    for (int i = 0; i < 6; i++) {
        boff[i] = bo;
        bo += ((u64)cvtn[i] * 2 + 15) & ~(u64)15;
    }
    boff[6] = HBF_OFF;
    boff[7] = YBF_OFF;
    for (int i = 0; i < 8; i++) {
        args.src[i] = d_in[cvtsrc[i]];
        args.dstoff[i] = boff[i];
        args.n[i] = cvtn[i];
    }
    const u16* cbe1 = (const u16*)(ws + boff[0]);
    const u16* cbe2 = (const u16*)(ws + boff[1]);
    const u16* cbn1 = (const u16*)(ws + boff[2]);
    const u16* cbn2 = (const u16*)(ws + boff[3]);
    const u16* cbf1 = (const u16*)(ws + boff[4]);
    const u16* cbf2 = (const u16*)(ws + boff[5]);

    // fragment-linear blocked weights
    BwArgs bwa;
    bwa.We1 = d_in[7];  bwa.We2 = d_in[9];  bwa.Wv = d_in[12]; bwa.Wa = d_in[13];
    bwa.Wc  = d_in[11]; bwa.Wo  = d_in[14]; bwa.Wn1 = d_in[15]; bwa.Wn2 = d_in[17];
    bwa.Wf1 = d_in[19]; bwa.Wf2 = d_in[21];
    bwa.b1 = BW_OFF;
    bwa.b2 = bwa.b1 + (u64)5*2*10*512*2;   // 102400 B
    bwa.b3 = bwa.b2 + (u64)5*10*512*2;     //  51200 B
    bwa.b4 = bwa.b3 + (u64)5*9*512*2;      //  46080 B
    bwa.b5 = bwa.b4 + (u64)4*8*512*2;      //  32768 B
    bwa.b6 = bwa.b5 + (u64)4*10*512*2;     //  40960 B
    bwa.b7 = bwa.b6 + (u64)5*8*512*2;      //  40960 B
    bwa.b8 = bwa.b7 + (u64)2*16*512*2;     //  32768 B
    const u16* We1P = (const u16*)(ws + bwa.b1);
    const u16* We2P = (const u16*)(ws + bwa.b2);
    const u16* W3P  = (const u16*)(ws + bwa.b3);
    const u16* WoP  = (const u16*)(ws + bwa.b4);
    const u16* Wn1P = (const u16*)(ws + bwa.b5);
    const u16* Wn2P = (const u16*)(ws + bwa.b6);
    const u16* Wf1P = (const u16*)(ws + bwa.b7);
    const u16* Wf2P = (const u16*)(ws + bwa.b8);

    hipMemsetAsync(d_ws, 0, MEMSET_BYTES, stream);

    preproc_kernel<<<256, 256, 0, stream>>>(h, flag, ws, args, bwa, dst, cnt);

    scan_kernel<<<1, 1024, 0, stream>>>(cnt, cursor);

    scatter_kernel<<<(N_EDGES + 255)/256, 256, 0, stream>>>(dst, cursor, perm);

    edge_kernel<<<N_EDGES/64, 256, 0, stream>>>(flag, hbf, coords, a, src, dst, perm,
                                                We1P, We2P, W3P, cbe1, cbe2,
                                                den, hagg, cacc);

    node_kernel<<<(N_NODES + 63)/64, 256, 0, stream>>>(
        flag, hbf, res, coords, ybf, den, hagg, cacc,
        WoP, Wn1P, Wn2P, Wf1P, Wf2P, cbn1, cbn2, cbf1, cbf2, d_out);
}